// Round 11
// baseline (463.759 us; speedup 1.0000x reference)
//
#include <hip/hip_runtime.h>

#define MDIM 8192
#define NDIM 4096
#define KDIM 4096

typedef __attribute__((ext_vector_type(8))) short short8;
typedef __attribute__((ext_vector_type(4))) float f32x4;
typedef __attribute__((ext_vector_type(16))) float f32x16;
typedef unsigned short u16;
typedef unsigned int u32;

__device__ __forceinline__ u16 f2bf(float f) {
  return __builtin_bit_cast(u16, static_cast<__bf16>(f));
}

// ---------------- prepass 1: x f32 -> bf16 in MFMA-fragment-linear layout --------
// unit = mblk*16384 + kblk*64 + lane holds A[mblk*32+(lane&31)][kblk*16+(lane>>5)*8+e]
__global__ __launch_bounds__(256) void cvt_xfrag_kernel(const float* __restrict__ x,
                                                        u16* __restrict__ xf) {
  const u32 u = blockIdx.x * 256 + threadIdx.x;  // 0..4194303
  const int lane = u & 63;
  const int kblk = (u >> 6) & 255;
  const int mblk = u >> 14;
  const int m = mblk * 32 + (lane & 31);
  const int k0 = kblk * 16 + (lane >> 5) * 8;
  const float* p = x + (size_t)m * KDIM + k0;
  const f32x4 a = *(const f32x4*)p;
  const f32x4 b = *(const f32x4*)(p + 4);
  short8 v;
#pragma unroll
  for (int j = 0; j < 4; ++j) {
    v[j]     = (short)f2bf(a[j]);
    v[4 + j] = (short)f2bf(b[j]);
  }
  *(short8*)(xf + (size_t)u * 8) = v;
}

// ---------------- prepass 2: dequant -> MFMA-fragment-linear Bp (r8-verified) ----
__global__ __launch_bounds__(256) void dequant_w_kernel(const int* __restrict__ qw,
                                                        const int* __restrict__ qz,
                                                        const float* __restrict__ sc,
                                                        u16* __restrict__ wt) {
  const int g = blockIdx.x * 256 + threadIdx.x;  // 0..524287
  const int n = g & (NDIM - 1);
  const int kp0 = (g >> 12) * 4;
  const float s = sc[n];
  const int zw = qz[n >> 3];
  const int zp1 = ((zw >> ((n & 7) * 4)) & 0xF) + 1;
  const float sz = -(float)zp1 * s;
  const int nblk = n >> 5;
  const int lnlo = n & 31;
#pragma unroll
  for (int i = 0; i < 4; ++i) {
    const int kp = kp0 + i;
    const int w = qw[(size_t)kp * NDIM + n];
    short8 v;
#pragma unroll
    for (int j = 0; j < 8; ++j)
      v[j] = (short)f2bf(fmaf((float)((w >> (4 * j)) & 0xF), s, sz));
    const int kblk = kp >> 1;
    const int lane = ((kp & 1) << 5) + lnlo;
    const size_t unit = (size_t)nblk * 16384 + (size_t)kblk * 64 + lane;
    *(short8*)(wt + unit * 8) = v;
  }
}

// ---------------- main GEMM: zero-LDS, zero-barrier fragment streaming ----------
// 8 waves (2 wrow x 4 wcol), per-wave 128x64 output, 32x32x16 MFMA.
// 256 K-steps; 4 register sets, load distance 4.

#define LOADSET(P, S) do {                                                    \
    _Pragma("unroll")                                                         \
    for (int f_ = 0; f_ < 4; ++f_)                                            \
      ra[P][f_] = *(const short8*)(pa[f_] + (size_t)(S) * 1024);              \
    _Pragma("unroll")                                                         \
    for (int g_ = 0; g_ < 2; ++g_)                                            \
      rb[P][g_] = *(const short8*)(pb[g_] + (size_t)(S) * 1024);              \
  } while (0)

#define MFMASET(P) do {                                                       \
    _Pragma("unroll")                                                         \
    for (int f_ = 0; f_ < 4; ++f_)                                            \
      _Pragma("unroll")                                                       \
      for (int g_ = 0; g_ < 2; ++g_)                                          \
        acc[f_][g_] = __builtin_amdgcn_mfma_f32_32x32x16_bf16(                \
            ra[P][f_], rb[P][g_], acc[f_][g_], 0, 0, 0);                      \
  } while (0)

__global__ __launch_bounds__(512) void qgemm_nolds(const u16* __restrict__ Af,
                                                   const u16* __restrict__ Bf,
                                                   float* __restrict__ out) {
  const int tid  = threadIdx.x;
  const int lane = tid & 63;
  const int wave = tid >> 6;
  const int wrow = wave >> 2;  // 0..1 -> 128 output rows
  const int wcol = wave & 3;   // 0..3 -> 64 output cols

  const int bid = blockIdx.x;
  const int sbi = bid >> 4, li = bid & 15;
  const int mb = (sbi & 7) * 4 + (li & 3);    // 0..31
  const int nb = (sbi >> 3) * 4 + (li >> 2);  // 0..15
  const int m0 = mb * 256, n0 = nb * 256;

  // fragment base pointers (byte): frag(s) at base + s*1024
  const char* pa[4];
#pragma unroll
  for (int fm = 0; fm < 4; ++fm) {
    const int mblk = mb * 8 + wrow * 4 + fm;
    pa[fm] = (const char*)Af + (size_t)mblk * 262144 + lane * 16;
  }
  const char* pb[2];
#pragma unroll
  for (int fn = 0; fn < 2; ++fn) {
    const int nblk = nb * 8 + wcol * 2 + fn;
    pb[fn] = (const char*)Bf + (size_t)nblk * 262144 + lane * 16;
  }

  f32x16 acc[4][2];
#pragma unroll
  for (int i = 0; i < 4; ++i)
#pragma unroll
    for (int j = 0; j < 2; ++j)
      acc[i][j] = (f32x16)(0.f);

  short8 ra[4][4];  // [set][fm]  (static indexing via unrolled loops)
  short8 rb[4][2];  // [set][fn]

  // prologue: sets 0..3 <- K-steps 0..3
#pragma unroll
  for (int p = 0; p < 4; ++p)
    LOADSET(p, p);

  // main loop: 64 iters x 4 K-steps; set p holds step s (s%4==p), reloads s+4
  for (int it = 0; it < 64; ++it) {
#pragma unroll
    for (int p = 0; p < 4; ++p) {
      const int s = it * 4 + p;
      MFMASET(p);
      LOADSET(p, (s + 4) & 255);  // wraps to dead reloads on final iter
    }
  }

  // epilogue: 32x32 C/D: col=lane&31, row=(reg&3)+8*(reg>>2)+4*(lane>>5)  [r8-verified]
  const int hi = lane >> 5;
#pragma unroll
  for (int fm = 0; fm < 4; ++fm) {
#pragma unroll
    for (int fn = 0; fn < 2; ++fn) {
      const f32x16 c = acc[fm][fn];
      const int gc = n0 + wcol * 64 + fn * 32 + (lane & 31);
      const int gr0 = m0 + wrow * 128 + fm * 32 + hi * 4;
#pragma unroll
      for (int rg = 0; rg < 16; ++rg) {
        const int gr = gr0 + (rg & 3) + 8 * (rg >> 2);
        out[(size_t)gr * NDIM + gc] = c[rg];
      }
    }
  }
}

// ---------------- fallback: fused f32-input kernel (r3, proven) ----------------
#define BM 128
#define BN 128
#define BK 64
#define NKT (KDIM / BK)
#define LDA 72
__global__ __launch_bounds__(256) void qgemm_fused_f32(
    const float* __restrict__ x, const int* __restrict__ qweight,
    const int* __restrict__ qzeros, const float* __restrict__ scales,
    float* __restrict__ out) {
  __shared__ __align__(16) short As[BM * LDA];
  __shared__ __align__(16) short Bs[BN * LDA];

  const int tid = threadIdx.x;
  const int lane = tid & 63;
  const int wave = tid >> 6;
  const int wr = wave >> 1, wc = wave & 1;
  const int bid = blockIdx.x;
  const int sbq = bid >> 4, li = bid & 15;
  const int mb = (sbq & 15) * 4 + (li & 3);
  const int nb = (sbq >> 4) * 4 + (li >> 2);
  const int m0 = mb * BM, n0 = nb * BN;

  const int ncol = tid & 127;
  const int kp_base = (tid >> 7) * 4;
  const int n_g = n0 + ncol;
  const float s = scales[n_g];
  const int zw = qzeros[n_g >> 3];
  const int zp1 = ((zw >> ((n_g & 7) * 4)) & 0xF) + 1;
  const float sz = -(float)zp1 * s;

  const int arow0 = tid >> 3;
  const int acol = (tid & 7) * 8;
  const int* qwp = qweight + (size_t)kp_base * NDIM + n_g;

  f32x4 af[8];
  {
    const float* xf = x + (size_t)(m0 + arow0) * KDIM + acol;
#pragma unroll
    for (int g = 0; g < 4; ++g) {
      af[2 * g]     = *(const f32x4*)(xf + (size_t)g * 32 * KDIM);
      af[2 * g + 1] = *(const f32x4*)(xf + (size_t)g * 32 * KDIM + 4);
    }
  }
  int qw0 = qwp[0], qw1 = qwp[NDIM], qw2 = qwp[2 * NDIM], qw3 = qwp[3 * NDIM];

  f32x4 acc[4][4];
#pragma unroll
  for (int i = 0; i < 4; ++i)
#pragma unroll
    for (int j = 0; j < 4; ++j)
      acc[i][j] = (f32x4)(0.f);

  const int lr = lane & 15, kh = lane >> 4;

  for (int kt = 0; kt < NKT; ++kt) {
    __syncthreads();
#pragma unroll
    for (int g = 0; g < 4; ++g) {
      short8 v;
#pragma unroll
      for (int j = 0; j < 4; ++j) {
        v[j]     = (short)f2bf(af[2 * g][j]);
        v[4 + j] = (short)f2bf(af[2 * g + 1][j]);
      }
      *(short8*)&As[(arow0 + g * 32) * LDA + acol] = v;
    }
    {
      const int qq[4] = {qw0, qw1, qw2, qw3};
#pragma unroll
      for (int r = 0; r < 4; ++r) {
        const int w = qq[r];
        short8 v;
#pragma unroll
        for (int j = 0; j < 8; ++j)
          v[j] = (short)f2bf(fmaf((float)((w >> (4 * j)) & 0xF), s, sz));
        *(short8*)&Bs[ncol * LDA + (kp_base + r) * 8] = v;
      }
    }
    if (kt + 1 < NKT) {
      const float* xp = x + (size_t)(m0 + arow0) * KDIM + (size_t)(kt + 1) * BK + acol;
#pragma unroll
      for (int g = 0; g < 4; ++g) {
        af[2 * g]     = *(const f32x4*)(xp + (size_t)g * 32 * KDIM);
        af[2 * g + 1] = *(const f32x4*)(xp + (size_t)g * 32 * KDIM + 4);
      }
      const int* p = qwp + (size_t)(kt + 1) * 8 * NDIM;
      qw0 = p[0]; qw1 = p[NDIM]; qw2 = p[2 * NDIM]; qw3 = p[3 * NDIM];
    }
    __syncthreads();
#pragma unroll
    for (int ks = 0; ks < 2; ++ks) {
      const int kb = (ks * 4 + kh) * 8;
      short8 a[4], bb[4];
#pragma unroll
      for (int mf = 0; mf < 4; ++mf)
        a[mf] = *(const short8*)&As[(wr * 64 + mf * 16 + lr) * LDA + kb];
#pragma unroll
      for (int nf = 0; nf < 4; ++nf)
        bb[nf] = *(const short8*)&Bs[(wc * 64 + nf * 16 + lr) * LDA + kb];
#pragma unroll
      for (int mf = 0; mf < 4; ++mf)
#pragma unroll
        for (int nf = 0; nf < 4; ++nf)
          acc[mf][nf] = __builtin_amdgcn_mfma_f32_16x16x32_bf16(a[mf], bb[nf], acc[mf][nf], 0, 0, 0);
    }
  }
#pragma unroll
  for (int mf = 0; mf < 4; ++mf)
#pragma unroll
    for (int nf = 0; nf < 4; ++nf) {
      const f32x4 c = acc[mf][nf];
      const int gc = n0 + wc * 64 + nf * 16 + lr;
#pragma unroll
      for (int rg = 0; rg < 4; ++rg)
        out[(size_t)(m0 + wr * 64 + mf * 16 + kh * 4 + rg) * NDIM + gc] = c[rg];
    }
}

extern "C" void kernel_launch(void* const* d_in, const int* in_sizes, int n_in,
                              void* d_out, int out_size, void* d_ws, size_t ws_size,
                              hipStream_t stream) {
  const float* x      = (const float*)d_in[0];  // fp16 ref stored as f32 on device
  const int* qweight  = (const int*)d_in[2];    // [K/8][N] int32
  const int* qzeros   = (const int*)d_in[3];    // [1][N/8] int32
  const float* scales = (const float*)d_in[4];  // fp16 ref stored as f32
  float* out = (float*)d_out;

  const size_t xb_bytes = (size_t)MDIM * KDIM * 2;  // 64 MB
  const size_t wt_bytes = (size_t)NDIM * KDIM * 2;  // 32 MB

  if (ws_size >= xb_bytes + wt_bytes) {
    u16* xf = (u16*)d_ws;
    u16* wt = (u16*)((char*)d_ws + xb_bytes);
    cvt_xfrag_kernel<<<16384, 256, 0, stream>>>(x, xf);
    dequant_w_kernel<<<2048, 256, 0, stream>>>(qweight, qzeros, scales, wt);
    const int grid = (MDIM / 256) * (NDIM / 256);  // 512
    qgemm_nolds<<<grid, 512, 0, stream>>>(xf, wt, out);
  } else {
    const int grid = (MDIM / BM) * (NDIM / BN);  // 2048
    qgemm_fused_f32<<<grid, 256, 0, stream>>>(x, qweight, qzeros, scales, out);
  }
}

// Round 12
// 422.477 us; speedup vs baseline: 1.0977x; 1.0977x over previous
//
#include <hip/hip_runtime.h>

#define MDIM 8192
#define NDIM 4096
#define KDIM 4096

typedef __attribute__((ext_vector_type(8))) short short8;
typedef __attribute__((ext_vector_type(4))) float f32x4;
typedef __attribute__((ext_vector_type(16))) float f32x16;
typedef unsigned short u16;
typedef unsigned int u32;

__device__ __forceinline__ u16 f2bf(float f) {
  return __builtin_bit_cast(u16, static_cast<__bf16>(f));
}

// ---------------- prepass 1: x f32 -> bf16, MFMA-fragment-linear (r11-verified) ----
// 16B unit u = mblk*16384 + kblk*64 + lane holds A[mblk*32+(lane&31)][kblk*16+(lane>>5)*8+e]
__global__ __launch_bounds__(256) void cvt_xfrag_kernel(const float* __restrict__ x,
                                                        u16* __restrict__ xf) {
  const u32 u = blockIdx.x * 256 + threadIdx.x;  // 0..4194303
  const int lane = u & 63;
  const int kblk = (u >> 6) & 255;
  const int mblk = u >> 14;
  const int m = mblk * 32 + (lane & 31);
  const int k0 = kblk * 16 + (lane >> 5) * 8;
  const float* p = x + (size_t)m * KDIM + k0;
  const f32x4 a = *(const f32x4*)p;
  const f32x4 b = *(const f32x4*)(p + 4);
  short8 v;
#pragma unroll
  for (int j = 0; j < 4; ++j) {
    v[j]     = (short)f2bf(a[j]);
    v[4 + j] = (short)f2bf(b[j]);
  }
  *(short8*)(xf + (size_t)u * 8) = v;
}

// ---------------- prepass 2: dequant -> MFMA-fragment-linear Bp (r8-verified) ----
__global__ __launch_bounds__(256) void dequant_w_kernel(const int* __restrict__ qw,
                                                        const int* __restrict__ qz,
                                                        const float* __restrict__ sc,
                                                        u16* __restrict__ wt) {
  const int g = blockIdx.x * 256 + threadIdx.x;  // 0..524287
  const int n = g & (NDIM - 1);
  const int kp0 = (g >> 12) * 4;
  const float s = sc[n];
  const int zw = qz[n >> 3];
  const int zp1 = ((zw >> ((n & 7) * 4)) & 0xF) + 1;
  const float sz = -(float)zp1 * s;
  const int nblk = n >> 5;
  const int lnlo = n & 31;
#pragma unroll
  for (int i = 0; i < 4; ++i) {
    const int kp = kp0 + i;
    const int w = qw[(size_t)kp * NDIM + n];
    short8 v;
#pragma unroll
    for (int j = 0; j < 8; ++j)
      v[j] = (short)f2bf(fmaf((float)((w >> (4 * j)) & 0xF), s, sz));
    const int kblk = kp >> 1;
    const int lane = ((kp & 1) << 5) + lnlo;
    const size_t unit = (size_t)nblk * 16384 + (size_t)kblk * 64 + lane;
    *(short8*)(wt + unit * 8) = v;
  }
}

// ---------------- main GEMM: 256x256, 32x32x16, A frag-linear LDS, B streamed ----
#define BAR()    __builtin_amdgcn_s_barrier()
#define FENCE()  __builtin_amdgcn_sched_barrier(0)
#define PRIO1()  __builtin_amdgcn_s_setprio(1)
#define PRIO0()  __builtin_amdgcn_s_setprio(0)

// stage A K-tile T into buffer BUF: 4 glds rounds, linear dest, frag-linear src
#define STGA(BUF, T) do {                                                     \
    _Pragma("unroll")                                                         \
    for (int r_ = 0; r_ < 4; ++r_) {                                          \
      __builtin_amdgcn_global_load_lds(                                       \
        (const __attribute__((address_space(1))) void*)                       \
          (pA4[r_] + (size_t)(T) * 4096),                                     \
        (__attribute__((address_space(3))) void*)                             \
          (AsB + (BUF) * 32768 + r_ * 8192 + tid * 16), 16, 0, 0);            \
    }                                                                         \
  } while (0)

// load K-tile TN's 8 B-fragments into register set DST (coalesced 1KB each)
#define LDB(DST, TN) do {                                                     \
    _Pragma("unroll")                                                         \
    for (int fn_ = 0; fn_ < 2; ++fn_)                                         \
      _Pragma("unroll")                                                       \
      for (int kw_ = 0; kw_ < 4; ++kw_)                                       \
        DST[fn_ * 4 + kw_] = *(const short8*)(pB0 + (size_t)fn_ * 262144 +    \
            (size_t)(TN) * 4096 + kw_ * 1024);                                \
  } while (0)

// one K-tile phase: LDB(t+1) | STGA(t+3) | 32 MFMA on tile t | barrier
#define PHASE(T, BUF, BUFS, BC, BN) do {                                      \
    const int tn_ = ((T) + 1) & 63;                                           \
    const int ts_ = ((T) + 3) & 63;                                           \
    LDB(BN, tn_);                                                             \
    FENCE();                                                                  \
    STGA(BUFS, ts_);                                                          \
    FENCE();                                                                  \
    PRIO1();                                                                  \
    _Pragma("unroll")                                                         \
    for (int kw_ = 0; kw_ < 4; ++kw_) {                                       \
      const char* b_ = AsB + (BUF) * 32768 + arb + kw_ * 1024;                \
      short8 aq0 = *(const short8*)(b_);                                      \
      short8 aq1 = *(const short8*)(b_ + 4096);                               \
      short8 aq2 = *(const short8*)(b_ + 8192);                               \
      short8 aq3 = *(const short8*)(b_ + 12288);                              \
      acc[0][0] = __builtin_amdgcn_mfma_f32_32x32x16_bf16(aq0, BC[0 * 4 + kw_], acc[0][0], 0, 0, 0); \
      acc[1][0] = __builtin_amdgcn_mfma_f32_32x32x16_bf16(aq1, BC[0 * 4 + kw_], acc[1][0], 0, 0, 0); \
      acc[2][0] = __builtin_amdgcn_mfma_f32_32x32x16_bf16(aq2, BC[0 * 4 + kw_], acc[2][0], 0, 0, 0); \
      acc[3][0] = __builtin_amdgcn_mfma_f32_32x32x16_bf16(aq3, BC[0 * 4 + kw_], acc[3][0], 0, 0, 0); \
      acc[0][1] = __builtin_amdgcn_mfma_f32_32x32x16_bf16(aq0, BC[1 * 4 + kw_], acc[0][1], 0, 0, 0); \
      acc[1][1] = __builtin_amdgcn_mfma_f32_32x32x16_bf16(aq1, BC[1 * 4 + kw_], acc[1][1], 0, 0, 0); \
      acc[2][1] = __builtin_amdgcn_mfma_f32_32x32x16_bf16(aq2, BC[1 * 4 + kw_], acc[2][1], 0, 0, 0); \
      acc[3][1] = __builtin_amdgcn_mfma_f32_32x32x16_bf16(aq3, BC[1 * 4 + kw_], acc[3][1], 0, 0, 0); \
    }                                                                         \
    PRIO0(); FENCE();                                                         \
    BAR(); FENCE();                                                           \
  } while (0)

__global__ __launch_bounds__(512, 2) void qgemm_fraglds(const u16* __restrict__ Af,
                                                        const u16* __restrict__ Bf,
                                                        float* __restrict__ out) {
  __shared__ __align__(16) char AsB[4 * 32768];  // 4-deep A K-tiles, fragment-linear

  const int tid  = threadIdx.x;
  const int lane = tid & 63;
  const int wave = tid >> 6;
  const int wrow = wave >> 2;  // 0..1 -> 128 output rows
  const int wcol = wave & 3;   // 0..3 -> 64 output cols

  const int bid = blockIdx.x;
  const int sbi = bid >> 4, li = bid & 15;
  const int mb = (sbi & 7) * 4 + (li & 3);    // 0..31
  const int nb = (sbi >> 3) * 4 + (li >> 2);  // 0..15
  const int m0 = mb * 256, n0 = nb * 256;

  // A staging source bases: dest unit (r*512+tid) -> mblk=2r+(tid>>8),
  // kw=(tid>>6)&3, lane=tid&63; src = frag-linear Af (+ T*4096B per K-tile)
  const char* pA4[4];
#pragma unroll
  for (int r = 0; r < 4; ++r) {
    pA4[r] = (const char*)Af +
             (size_t)(mb * 8 + 2 * r + (tid >> 8)) * 262144 +
             (size_t)(((tid >> 6) & 3) * 64 + (tid & 63)) * 16;
  }

  // B base: fragment-linear, this wave's nblk pair
  const char* pB0 = (const char*)Bf +
      ((size_t)(nb * 8) + wcol * 2) * 262144 + lane * 16;

  // A fragment read base: unit = (wrow*4+fm)*256 + kw*64 + lane (contiguous b128)
  const int arb = wrow * 16384 + lane * 16;

  f32x16 acc[4][2];
#pragma unroll
  for (int i = 0; i < 4; ++i)
#pragma unroll
    for (int j = 0; j < 2; ++j)
      acc[i][j] = (f32x16)(0.f);

  short8 bA[8], bB[8];

  // ---- prologue: A(0),A(1),A(2) staged; B(0) in regs; force stages ----
  STGA(0, 0);
  STGA(1, 1);
  STGA(2, 2);
  LDB(bA, 0);
  asm volatile("s_waitcnt vmcnt(8)" ::: "memory");  // forces STGA(0..2); LDB auto-waited
  BAR(); FENCE();

  // ---- main loop: 16 iters x 4 K-tiles; buf = t&3 ----
  for (int it = 0; it < 16; ++it) {
    const int tb = it * 4;
    PHASE(tb + 0, 0, 3, bA, bB);
    PHASE(tb + 1, 1, 0, bB, bA);
    PHASE(tb + 2, 2, 1, bA, bB);
    PHASE(tb + 3, 3, 2, bB, bA);
  }

  asm volatile("s_waitcnt vmcnt(0)" ::: "memory");  // drain wrapped dead stages

  // ---- epilogue: 32x32 C/D: col=lane&31, row=(reg&3)+8*(reg>>2)+4*(lane>>5) ----
  const int hi = lane >> 5;
#pragma unroll
  for (int fm = 0; fm < 4; ++fm) {
#pragma unroll
    for (int fn = 0; fn < 2; ++fn) {
      const f32x16 c = acc[fm][fn];
      const int gc = n0 + wcol * 64 + fn * 32 + (lane & 31);
      const int gr0 = m0 + wrow * 128 + fm * 32 + hi * 4;
#pragma unroll
      for (int rg = 0; rg < 16; ++rg) {
        const int gr = gr0 + (rg & 3) + 8 * (rg >> 2);
        out[(size_t)gr * NDIM + gc] = c[rg];
      }
    }
  }
}

// ---------------- fallback: fused f32-input kernel (r3, proven) ----------------
#define BM 128
#define BN 128
#define BK 64
#define NKT (KDIM / BK)
#define LDA 72
__global__ __launch_bounds__(256) void qgemm_fused_f32(
    const float* __restrict__ x, const int* __restrict__ qweight,
    const int* __restrict__ qzeros, const float* __restrict__ scales,
    float* __restrict__ out) {
  __shared__ __align__(16) short As[BM * LDA];
  __shared__ __align__(16) short Bs[BN * LDA];

  const int tid = threadIdx.x;
  const int lane = tid & 63;
  const int wave = tid >> 6;
  const int wr = wave >> 1, wc = wave & 1;
  const int bid = blockIdx.x;
  const int sbq = bid >> 4, li = bid & 15;
  const int mb = (sbq & 15) * 4 + (li & 3);
  const int nb = (sbq >> 4) * 4 + (li >> 2);
  const int m0 = mb * BM, n0 = nb * BN;

  const int ncol = tid & 127;
  const int kp_base = (tid >> 7) * 4;
  const int n_g = n0 + ncol;
  const float s = scales[n_g];
  const int zw = qzeros[n_g >> 3];
  const int zp1 = ((zw >> ((n_g & 7) * 4)) & 0xF) + 1;
  const float sz = -(float)zp1 * s;

  const int arow0 = tid >> 3;
  const int acol = (tid & 7) * 8;
  const int* qwp = qweight + (size_t)kp_base * NDIM + n_g;

  f32x4 af[8];
  {
    const float* xf = x + (size_t)(m0 + arow0) * KDIM + acol;
#pragma unroll
    for (int g = 0; g < 4; ++g) {
      af[2 * g]     = *(const f32x4*)(xf + (size_t)g * 32 * KDIM);
      af[2 * g + 1] = *(const f32x4*)(xf + (size_t)g * 32 * KDIM + 4);
    }
  }
  int qw0 = qwp[0], qw1 = qwp[NDIM], qw2 = qwp[2 * NDIM], qw3 = qwp[3 * NDIM];

  f32x4 acc[4][4];
#pragma unroll
  for (int i = 0; i < 4; ++i)
#pragma unroll
    for (int j = 0; j < 4; ++j)
      acc[i][j] = (f32x4)(0.f);

  const int lr = lane & 15, kh = lane >> 4;

  for (int kt = 0; kt < NKT; ++kt) {
    __syncthreads();
#pragma unroll
    for (int g = 0; g < 4; ++g) {
      short8 v;
#pragma unroll
      for (int j = 0; j < 4; ++j) {
        v[j]     = (short)f2bf(af[2 * g][j]);
        v[4 + j] = (short)f2bf(af[2 * g + 1][j]);
      }
      *(short8*)&As[(arow0 + g * 32) * LDA + acol] = v;
    }
    {
      const int qq[4] = {qw0, qw1, qw2, qw3};
#pragma unroll
      for (int r = 0; r < 4; ++r) {
        const int w = qq[r];
        short8 v;
#pragma unroll
        for (int j = 0; j < 8; ++j)
          v[j] = (short)f2bf(fmaf((float)((w >> (4 * j)) & 0xF), s, sz));
        *(short8*)&Bs[ncol * LDA + (kp_base + r) * 8] = v;
      }
    }
    if (kt + 1 < NKT) {
      const float* xp = x + (size_t)(m0 + arow0) * KDIM + (size_t)(kt + 1) * BK + acol;
#pragma unroll
      for (int g = 0; g < 4; ++g) {
        af[2 * g]     = *(const f32x4*)(xp + (size_t)g * 32 * KDIM);
        af[2 * g + 1] = *(const f32x4*)(xp + (size_t)g * 32 * KDIM + 4);
      }
      const int* p = qwp + (size_t)(kt + 1) * 8 * NDIM;
      qw0 = p[0]; qw1 = p[NDIM]; qw2 = p[2 * NDIM]; qw3 = p[3 * NDIM];
    }
    __syncthreads();
#pragma unroll
    for (int ks = 0; ks < 2; ++ks) {
      const int kb = (ks * 4 + kh) * 8;
      short8 a[4], bb[4];
#pragma unroll
      for (int mf = 0; mf < 4; ++mf)
        a[mf] = *(const short8*)&As[(wr * 64 + mf * 16 + lr) * LDA + kb];
#pragma unroll
      for (int nf = 0; nf < 4; ++nf)
        bb[nf] = *(const short8*)&Bs[(wc * 64 + nf * 16 + lr) * LDA + kb];
#pragma unroll
      for (int mf = 0; mf < 4; ++mf)
#pragma unroll
        for (int nf = 0; nf < 4; ++nf)
          acc[mf][nf] = __builtin_amdgcn_mfma_f32_16x16x32_bf16(a[mf], bb[nf], acc[mf][nf], 0, 0, 0);
    }
  }
#pragma unroll
  for (int mf = 0; mf < 4; ++mf)
#pragma unroll
    for (int nf = 0; nf < 4; ++nf) {
      const f32x4 c = acc[mf][nf];
      const int gc = n0 + wc * 64 + nf * 16 + lr;
#pragma unroll
      for (int rg = 0; rg < 4; ++rg)
        out[(size_t)(m0 + wr * 64 + mf * 16 + kh * 4 + rg) * NDIM + gc] = c[rg];
    }
}

extern "C" void kernel_launch(void* const* d_in, const int* in_sizes, int n_in,
                              void* d_out, int out_size, void* d_ws, size_t ws_size,
                              hipStream_t stream) {
  const float* x      = (const float*)d_in[0];  // fp16 ref stored as f32 on device
  const int* qweight  = (const int*)d_in[2];    // [K/8][N] int32
  const int* qzeros   = (const int*)d_in[3];    // [1][N/8] int32
  const float* scales = (const float*)d_in[4];  // fp16 ref stored as f32
  float* out = (float*)d_out;

  const size_t xb_bytes = (size_t)MDIM * KDIM * 2;  // 64 MB
  const size_t wt_bytes = (size_t)NDIM * KDIM * 2;  // 32 MB

  if (ws_size >= xb_bytes + wt_bytes) {
    u16* xf = (u16*)d_ws;
    u16* wt = (u16*)((char*)d_ws + xb_bytes);
    cvt_xfrag_kernel<<<16384, 256, 0, stream>>>(x, xf);
    dequant_w_kernel<<<2048, 256, 0, stream>>>(qweight, qzeros, scales, wt);
    const int grid = (MDIM / 256) * (NDIM / 256);  // 512
    qgemm_fraglds<<<grid, 512, 0, stream>>>(xf, wt, out);
  } else {
    const int grid = (MDIM / BM) * (NDIM / BN);  // 2048
    qgemm_fused_f32<<<grid, 256, 0, stream>>>(x, qweight, qzeros, scales, out);
  }
}

// Round 13
// 303.866 us; speedup vs baseline: 1.5262x; 1.3903x over previous
//
#include <hip/hip_runtime.h>

#define MDIM 8192
#define NDIM 4096
#define KDIM 4096

typedef __attribute__((ext_vector_type(8))) short short8;
typedef __attribute__((ext_vector_type(4))) float f32x4;
typedef __attribute__((ext_vector_type(16))) float f32x16;
typedef unsigned short u16;
typedef unsigned int u32;

__device__ __forceinline__ u16 f2bf(float f) {
  return __builtin_bit_cast(u16, static_cast<__bf16>(f));
}

// ---------------- prepass 1: x f32 -> bf16, MFMA-fragment-linear (r11/r12-verified) ----
// 16B unit u = mblk*16384 + kblk*64 + lane holds A[mblk*32+(lane&31)][kblk*16+(lane>>5)*8+e]
__global__ __launch_bounds__(256) void cvt_xfrag_kernel(const float* __restrict__ x,
                                                        u16* __restrict__ xf) {
  const u32 u = blockIdx.x * 256 + threadIdx.x;  // 0..4194303
  const int lane = u & 63;
  const int kblk = (u >> 6) & 255;
  const int mblk = u >> 14;
  const int m = mblk * 32 + (lane & 31);
  const int k0 = kblk * 16 + (lane >> 5) * 8;
  const float* p = x + (size_t)m * KDIM + k0;
  const f32x4 a = *(const f32x4*)p;
  const f32x4 b = *(const f32x4*)(p + 4);
  short8 v;
#pragma unroll
  for (int j = 0; j < 4; ++j) {
    v[j]     = (short)f2bf(a[j]);
    v[4 + j] = (short)f2bf(b[j]);
  }
  *(short8*)(xf + (size_t)u * 8) = v;
}

// ---------------- prepass 2: dequant -> MFMA-fragment-linear Bp (r8-verified) ----
__global__ __launch_bounds__(256) void dequant_w_kernel(const int* __restrict__ qw,
                                                        const int* __restrict__ qz,
                                                        const float* __restrict__ sc,
                                                        u16* __restrict__ wt) {
  const int g = blockIdx.x * 256 + threadIdx.x;  // 0..524287
  const int n = g & (NDIM - 1);
  const int kp0 = (g >> 12) * 4;
  const float s = sc[n];
  const int zw = qz[n >> 3];
  const int zp1 = ((zw >> ((n & 7) * 4)) & 0xF) + 1;
  const float sz = -(float)zp1 * s;
  const int nblk = n >> 5;
  const int lnlo = n & 31;
#pragma unroll
  for (int i = 0; i < 4; ++i) {
    const int kp = kp0 + i;
    const int w = qw[(size_t)kp * NDIM + n];
    short8 v;
#pragma unroll
    for (int j = 0; j < 8; ++j)
      v[j] = (short)f2bf(fmaf((float)((w >> (4 * j)) & 0xF), s, sz));
    const int kblk = kp >> 1;
    const int lane = ((kp & 1) << 5) + lnlo;
    const size_t unit = (size_t)nblk * 16384 + (size_t)kblk * 64 + lane;
    *(short8*)(wt + unit * 8) = v;
  }
}

// ---------------- main GEMM: r8 schedule (VM4 per phase) + fragment-linear A ----
#define BAR()    __builtin_amdgcn_s_barrier()
#define FENCE()  __builtin_amdgcn_sched_barrier(0)
#define VM4()    asm volatile("s_waitcnt vmcnt(4)" ::: "memory")
#define PRIO1()  __builtin_amdgcn_s_setprio(1)
#define PRIO0()  __builtin_amdgcn_s_setprio(0)

// stage A K-tile T into buffer BUF: 4 glds, linear dest, frag-linear src
#define STGA(BUF, T) do {                                                     \
    _Pragma("unroll")                                                         \
    for (int r_ = 0; r_ < 4; ++r_) {                                          \
      __builtin_amdgcn_global_load_lds(                                       \
        (const __attribute__((address_space(1))) void*)                       \
          (pA4[r_] + (size_t)(T) * 4096),                                     \
        (__attribute__((address_space(3))) void*)                             \
          (AsB + (BUF) * 32768 + r_ * 8192 + tid * 16), 16, 0, 0);            \
    }                                                                         \
  } while (0)

// load K-tile TN's 8 B-fragments into register set DST (coalesced 1KB each)
#define LDB(DST, TN) do {                                                     \
    _Pragma("unroll")                                                         \
    for (int fn_ = 0; fn_ < 2; ++fn_)                                         \
      _Pragma("unroll")                                                       \
      for (int kw_ = 0; kw_ < 4; ++kw_)                                       \
        DST[fn_ * 4 + kw_] = *(const short8*)(pB0 + (size_t)fn_ * 262144 +    \
            (size_t)(TN) * 4096 + kw_ * 1024);                                \
  } while (0)

// one K-tile phase (r8 structure verbatim; A-reads contiguous frag-linear)
#define PHASE(T, BUF, BUFS, BC, BN) do {                                      \
    const int tn_ = ((T) + 1) & 63;                                           \
    const int ts_ = ((T) + 3) & 63;                                           \
    LDB(BN, tn_);                                                             \
    STGA(BUFS, ts_);                                                          \
    FENCE();                                                                  \
    PRIO1();                                                                  \
    _Pragma("unroll")                                                         \
    for (int kw_ = 0; kw_ < 4; ++kw_) {                                       \
      const char* b_ = AsB + (BUF) * 32768 + arb + kw_ * 1024;                \
      short8 aq0 = *(const short8*)(b_);                                      \
      short8 aq1 = *(const short8*)(b_ + 4096);                               \
      short8 aq2 = *(const short8*)(b_ + 8192);                               \
      short8 aq3 = *(const short8*)(b_ + 12288);                              \
      acc[0][0] = __builtin_amdgcn_mfma_f32_32x32x16_bf16(aq0, BC[0 * 4 + kw_], acc[0][0], 0, 0, 0); \
      acc[1][0] = __builtin_amdgcn_mfma_f32_32x32x16_bf16(aq1, BC[0 * 4 + kw_], acc[1][0], 0, 0, 0); \
      acc[2][0] = __builtin_amdgcn_mfma_f32_32x32x16_bf16(aq2, BC[0 * 4 + kw_], acc[2][0], 0, 0, 0); \
      acc[3][0] = __builtin_amdgcn_mfma_f32_32x32x16_bf16(aq3, BC[0 * 4 + kw_], acc[3][0], 0, 0, 0); \
      acc[0][1] = __builtin_amdgcn_mfma_f32_32x32x16_bf16(aq0, BC[1 * 4 + kw_], acc[0][1], 0, 0, 0); \
      acc[1][1] = __builtin_amdgcn_mfma_f32_32x32x16_bf16(aq1, BC[1 * 4 + kw_], acc[1][1], 0, 0, 0); \
      acc[2][1] = __builtin_amdgcn_mfma_f32_32x32x16_bf16(aq2, BC[1 * 4 + kw_], acc[2][1], 0, 0, 0); \
      acc[3][1] = __builtin_amdgcn_mfma_f32_32x32x16_bf16(aq3, BC[1 * 4 + kw_], acc[3][1], 0, 0, 0); \
    }                                                                         \
    PRIO0(); FENCE();                                                         \
    VM4(); BAR(); FENCE();                                                    \
  } while (0)

__global__ __launch_bounds__(512, 2) void qgemm_r13(const u16* __restrict__ Af,
                                                    const u16* __restrict__ Bf,
                                                    float* __restrict__ out) {
  __shared__ __align__(16) char AsB[4 * 32768];  // 4-deep A K-tiles, fragment-linear

  const int tid  = threadIdx.x;
  const int lane = tid & 63;
  const int wave = tid >> 6;
  const int wrow = wave >> 2;  // 0..1 -> 128 output rows
  const int wcol = wave & 3;   // 0..3 -> 64 output cols

  const int bid = blockIdx.x;
  const int sbi = bid >> 4, li = bid & 15;
  const int mb = (sbi & 7) * 4 + (li & 3);    // 0..31
  const int nb = (sbi >> 3) * 4 + (li >> 2);  // 0..15
  const int m0 = mb * 256, n0 = nb * 256;

  // A staging sources: dest unit (r*512+tid) -> mblk_local=2r+(tid>>8),
  // kw=(tid>>6)&3, lane=tid&63; frag-linear Af, +T*4096B per K-tile (r12-verified)
  const char* pA4[4];
#pragma unroll
  for (int r = 0; r < 4; ++r) {
    pA4[r] = (const char*)Af +
             (size_t)(mb * 8 + 2 * r + (tid >> 8)) * 262144 +
             (size_t)(((tid >> 6) & 3) * 64 + (tid & 63)) * 16;
  }

  // B base: fragment-linear, this wave's nblk pair (r8-verified)
  const char* pB0 = (const char*)Bf +
      ((size_t)(nb * 8) + wcol * 2) * 262144 + lane * 16;

  // A fragment read base: byte = (wrow*4+fm)*4096 + kw*1024 + lane*16 (contiguous b128)
  const int arb = wrow * 16384 + lane * 16;

  f32x16 acc[4][2];
#pragma unroll
  for (int i = 0; i < 4; ++i)
#pragma unroll
    for (int j = 0; j < 2; ++j)
      acc[i][j] = (f32x16)(0.f);

  short8 bA[8], bB[8];

  // ---- prologue (r8 verbatim): A(0),A(1),A(2) staged; B(0) in flight ----
  STGA(0, 0);
  STGA(1, 1);
  STGA(2, 2);
  LDB(bA, 0);
  asm volatile("s_waitcnt vmcnt(8)" ::: "memory");  // forces STGA(0..2); bA auto-waited
  BAR(); FENCE();

  // ---- main loop: 16 iters x 4 K-tiles; buf = t&3 ----
  for (int it = 0; it < 16; ++it) {
    const int tb = it * 4;
    PHASE(tb + 0, 0, 3, bA, bB);
    PHASE(tb + 1, 1, 0, bB, bA);
    PHASE(tb + 2, 2, 1, bA, bB);
    PHASE(tb + 3, 3, 2, bB, bA);
  }

  asm volatile("s_waitcnt vmcnt(0)" ::: "memory");  // drain wrapped dead stages

  // ---- epilogue: 32x32 C/D: col=lane&31, row=(reg&3)+8*(reg>>2)+4*(lane>>5) ----
  const int hi = lane >> 5;
#pragma unroll
  for (int fm = 0; fm < 4; ++fm) {
#pragma unroll
    for (int fn = 0; fn < 2; ++fn) {
      const f32x16 c = acc[fm][fn];
      const int gc = n0 + wcol * 64 + fn * 32 + (lane & 31);
      const int gr0 = m0 + wrow * 128 + fm * 32 + hi * 4;
#pragma unroll
      for (int rg = 0; rg < 16; ++rg) {
        const int gr = gr0 + (rg & 3) + 8 * (rg >> 2);
        out[(size_t)gr * NDIM + gc] = c[rg];
      }
    }
  }
}

// ---------------- fallback: fused f32-input kernel (r3, proven) ----------------
#define BM 128
#define BN 128
#define BK 64
#define NKT (KDIM / BK)
#define LDA 72
__global__ __launch_bounds__(256) void qgemm_fused_f32(
    const float* __restrict__ x, const int* __restrict__ qweight,
    const int* __restrict__ qzeros, const float* __restrict__ scales,
    float* __restrict__ out) {
  __shared__ __align__(16) short As[BM * LDA];
  __shared__ __align__(16) short Bs[BN * LDA];

  const int tid = threadIdx.x;
  const int lane = tid & 63;
  const int wave = tid >> 6;
  const int wr = wave >> 1, wc = wave & 1;
  const int bid = blockIdx.x;
  const int sbq = bid >> 4, li = bid & 15;
  const int mb = (sbq & 15) * 4 + (li & 3);
  const int nb = (sbq >> 4) * 4 + (li >> 2);
  const int m0 = mb * BM, n0 = nb * BN;

  const int ncol = tid & 127;
  const int kp_base = (tid >> 7) * 4;
  const int n_g = n0 + ncol;
  const float s = scales[n_g];
  const int zw = qzeros[n_g >> 3];
  const int zp1 = ((zw >> ((n_g & 7) * 4)) & 0xF) + 1;
  const float sz = -(float)zp1 * s;

  const int arow0 = tid >> 3;
  const int acol = (tid & 7) * 8;
  const int* qwp = qweight + (size_t)kp_base * NDIM + n_g;

  f32x4 af[8];
  {
    const float* xf = x + (size_t)(m0 + arow0) * KDIM + acol;
#pragma unroll
    for (int g = 0; g < 4; ++g) {
      af[2 * g]     = *(const f32x4*)(xf + (size_t)g * 32 * KDIM);
      af[2 * g + 1] = *(const f32x4*)(xf + (size_t)g * 32 * KDIM + 4);
    }
  }
  int qw0 = qwp[0], qw1 = qwp[NDIM], qw2 = qwp[2 * NDIM], qw3 = qwp[3 * NDIM];

  f32x4 acc[4][4];
#pragma unroll
  for (int i = 0; i < 4; ++i)
#pragma unroll
    for (int j = 0; j < 4; ++j)
      acc[i][j] = (f32x4)(0.f);

  const int lr = lane & 15, kh = lane >> 4;

  for (int kt = 0; kt < NKT; ++kt) {
    __syncthreads();
#pragma unroll
    for (int g = 0; g < 4; ++g) {
      short8 v;
#pragma unroll
      for (int j = 0; j < 4; ++j) {
        v[j]     = (short)f2bf(af[2 * g][j]);
        v[4 + j] = (short)f2bf(af[2 * g + 1][j]);
      }
      *(short8*)&As[(arow0 + g * 32) * LDA + acol] = v;
    }
    {
      const int qq[4] = {qw0, qw1, qw2, qw3};
#pragma unroll
      for (int r = 0; r < 4; ++r) {
        const int w = qq[r];
        short8 v;
#pragma unroll
        for (int j = 0; j < 8; ++j)
          v[j] = (short)f2bf(fmaf((float)((w >> (4 * j)) & 0xF), s, sz));
        *(short8*)&Bs[ncol * LDA + (kp_base + r) * 8] = v;
      }
    }
    if (kt + 1 < NKT) {
      const float* xp = x + (size_t)(m0 + arow0) * KDIM + (size_t)(kt + 1) * BK + acol;
#pragma unroll
      for (int g = 0; g < 4; ++g) {
        af[2 * g]     = *(const f32x4*)(xp + (size_t)g * 32 * KDIM);
        af[2 * g + 1] = *(const f32x4*)(xp + (size_t)g * 32 * KDIM + 4);
      }
      const int* p = qwp + (size_t)(kt + 1) * 8 * NDIM;
      qw0 = p[0]; qw1 = p[NDIM]; qw2 = p[2 * NDIM]; qw3 = p[3 * NDIM];
    }
    __syncthreads();
#pragma unroll
    for (int ks = 0; ks < 2; ++ks) {
      const int kb = (ks * 4 + kh) * 8;
      short8 a[4], bb[4];
#pragma unroll
      for (int mf = 0; mf < 4; ++mf)
        a[mf] = *(const short8*)&As[(wr * 64 + mf * 16 + lr) * LDA + kb];
#pragma unroll
      for (int nf = 0; nf < 4; ++nf)
        bb[nf] = *(const short8*)&Bs[(wc * 64 + nf * 16 + lr) * LDA + kb];
#pragma unroll
      for (int mf = 0; mf < 4; ++mf)
#pragma unroll
        for (int nf = 0; nf < 4; ++nf)
          acc[mf][nf] = __builtin_amdgcn_mfma_f32_16x16x32_bf16(a[mf], bb[nf], acc[mf][nf], 0, 0, 0);
    }
  }
#pragma unroll
  for (int mf = 0; mf < 4; ++mf)
#pragma unroll
    for (int nf = 0; nf < 4; ++nf) {
      const f32x4 c = acc[mf][nf];
      const int gc = n0 + wc * 64 + nf * 16 + lr;
#pragma unroll
      for (int rg = 0; rg < 4; ++rg)
        out[(size_t)(m0 + wr * 64 + mf * 16 + kh * 4 + rg) * NDIM + gc] = c[rg];
    }
}

extern "C" void kernel_launch(void* const* d_in, const int* in_sizes, int n_in,
                              void* d_out, int out_size, void* d_ws, size_t ws_size,
                              hipStream_t stream) {
  const float* x      = (const float*)d_in[0];  // fp16 ref stored as f32 on device
  const int* qweight  = (const int*)d_in[2];    // [K/8][N] int32
  const int* qzeros   = (const int*)d_in[3];    // [1][N/8] int32
  const float* scales = (const float*)d_in[4];  // fp16 ref stored as f32
  float* out = (float*)d_out;

  const size_t xb_bytes = (size_t)MDIM * KDIM * 2;  // 64 MB
  const size_t wt_bytes = (size_t)NDIM * KDIM * 2;  // 32 MB

  if (ws_size >= xb_bytes + wt_bytes) {
    u16* xf = (u16*)d_ws;
    u16* wt = (u16*)((char*)d_ws + xb_bytes);
    cvt_xfrag_kernel<<<16384, 256, 0, stream>>>(x, xf);
    dequant_w_kernel<<<2048, 256, 0, stream>>>(qweight, qzeros, scales, wt);
    const int grid = (MDIM / 256) * (NDIM / 256);  // 512
    qgemm_r13<<<grid, 512, 0, stream>>>(xf, wt, out);
  } else {
    const int grid = (MDIM / BM) * (NDIM / BN);  // 2048
    qgemm_fused_f32<<<grid, 256, 0, stream>>>(x, qweight, qzeros, scales, out);
  }
}

// Round 14
// 296.074 us; speedup vs baseline: 1.5664x; 1.0263x over previous
//
#include <hip/hip_runtime.h>

#define MDIM 8192
#define NDIM 4096
#define KDIM 4096

typedef __attribute__((ext_vector_type(8))) short short8;
typedef __attribute__((ext_vector_type(4))) float f32x4;
typedef __attribute__((ext_vector_type(16))) float f32x16;
typedef unsigned short u16;
typedef unsigned int u32;

__device__ __forceinline__ u16 f2bf(float f) {
  return __builtin_bit_cast(u16, static_cast<__bf16>(f));
}

// ---------------- merged prepass: cvt x -> frag-linear bf16  +  dequant W ----------------
// cvt (blocks 0..16383): unit u = mblk*16384 + kblk*64 + lane holds
//   A[mblk*32+(lane&31)][kblk*16+(lane>>5)*8+e]   (r11/r12/r13-verified)
// dequant (blocks 16384..18431): Bp unit = nblk*16384 + kblk*64 + lane  (r8-verified)
__global__ __launch_bounds__(256) void prep_kernel(const float* __restrict__ x,
                                                   u16* __restrict__ xf,
                                                   const int* __restrict__ qw,
                                                   const int* __restrict__ qz,
                                                   const float* __restrict__ sc,
                                                   u16* __restrict__ wt) {
  const int b = blockIdx.x;
  if (b < 16384) {
    const u32 u = b * 256 + threadIdx.x;  // 0..4194303
    const int lane = u & 63;
    const int kblk = (u >> 6) & 255;
    const int mblk = u >> 14;
    const int m = mblk * 32 + (lane & 31);
    const int k0 = kblk * 16 + (lane >> 5) * 8;
    const float* p = x + (size_t)m * KDIM + k0;
    const f32x4 a = *(const f32x4*)p;
    const f32x4 bb = *(const f32x4*)(p + 4);
    short8 v;
#pragma unroll
    for (int j = 0; j < 4; ++j) {
      v[j]     = (short)f2bf(a[j]);
      v[4 + j] = (short)f2bf(bb[j]);
    }
    *(short8*)(xf + (size_t)u * 8) = v;
  } else {
    const int g = (b - 16384) * 256 + threadIdx.x;  // 0..524287
    const int n = g & (NDIM - 1);
    const int kp0 = (g >> 12) * 4;
    const float s = sc[n];
    const int zw = qz[n >> 3];
    const int zp1 = ((zw >> ((n & 7) * 4)) & 0xF) + 1;
    const float sz = -(float)zp1 * s;
    const int nblk = n >> 5;
    const int lnlo = n & 31;
#pragma unroll
    for (int i = 0; i < 4; ++i) {
      const int kp = kp0 + i;
      const int w = qw[(size_t)kp * NDIM + n];
      short8 v;
#pragma unroll
      for (int j = 0; j < 8; ++j)
        v[j] = (short)f2bf(fmaf((float)((w >> (4 * j)) & 0xF), s, sz));
      const int kblk = kp >> 1;
      const int lane = ((kp & 1) << 5) + lnlo;
      const size_t unit = (size_t)nblk * 16384 + (size_t)kblk * 64 + lane;
      *(short8*)(wt + unit * 8) = v;
    }
  }
}

// ---------------- main GEMM: 256x256, 32x32x16, frag-linear A LDS, B streamed ----------
// r13 components, barrier cadence halved: 2 K-tiles per barrier.
#define BAR()    __builtin_amdgcn_s_barrier()
#define FENCE()  __builtin_amdgcn_sched_barrier(0)
#define VM8()    asm volatile("s_waitcnt vmcnt(8)" ::: "memory")
#define PRIO1()  __builtin_amdgcn_s_setprio(1)
#define PRIO0()  __builtin_amdgcn_s_setprio(0)

// stage A K-tile T into buffer BUF: 4 glds, linear dest, frag-linear src (r13-verified)
#define STGA(BUF, T) do {                                                     \
    _Pragma("unroll")                                                         \
    for (int r_ = 0; r_ < 4; ++r_) {                                          \
      __builtin_amdgcn_global_load_lds(                                       \
        (const __attribute__((address_space(1))) void*)                       \
          (pA4[r_] + (size_t)(T) * 4096),                                     \
        (__attribute__((address_space(3))) void*)                             \
          (AsB + (BUF) * 32768 + r_ * 8192 + tid * 16), 16, 0, 0);            \
    }                                                                         \
  } while (0)

// load K-tile TN's 8 B-fragments into register set DST (coalesced 1KB each)
#define LDB(DST, TN) do {                                                     \
    _Pragma("unroll")                                                         \
    for (int fn_ = 0; fn_ < 2; ++fn_)                                         \
      _Pragma("unroll")                                                       \
      for (int kw_ = 0; kw_ < 4; ++kw_)                                       \
        DST[fn_ * 4 + kw_] = *(const short8*)(pB0 + (size_t)fn_ * 262144 +    \
            (size_t)(TN) * 4096 + kw_ * 1024);                                \
  } while (0)

// MFMA one K-tile from A-LDS buffer BUF with B register set BSET (r13 inner)
#define MTILE(BUF, BSET) do {                                                 \
    _Pragma("unroll")                                                         \
    for (int kw_ = 0; kw_ < 4; ++kw_) {                                       \
      const char* b_ = AsB + (BUF) * 32768 + arb + kw_ * 1024;                \
      short8 aq0 = *(const short8*)(b_);                                      \
      short8 aq1 = *(const short8*)(b_ + 4096);                               \
      short8 aq2 = *(const short8*)(b_ + 8192);                               \
      short8 aq3 = *(const short8*)(b_ + 12288);                              \
      acc[0][0] = __builtin_amdgcn_mfma_f32_32x32x16_bf16(aq0, BSET[0 * 4 + kw_], acc[0][0], 0, 0, 0); \
      acc[1][0] = __builtin_amdgcn_mfma_f32_32x32x16_bf16(aq1, BSET[0 * 4 + kw_], acc[1][0], 0, 0, 0); \
      acc[2][0] = __builtin_amdgcn_mfma_f32_32x32x16_bf16(aq2, BSET[0 * 4 + kw_], acc[2][0], 0, 0, 0); \
      acc[3][0] = __builtin_amdgcn_mfma_f32_32x32x16_bf16(aq3, BSET[0 * 4 + kw_], acc[3][0], 0, 0, 0); \
      acc[0][1] = __builtin_amdgcn_mfma_f32_32x32x16_bf16(aq0, BSET[1 * 4 + kw_], acc[0][1], 0, 0, 0); \
      acc[1][1] = __builtin_amdgcn_mfma_f32_32x32x16_bf16(aq1, BSET[1 * 4 + kw_], acc[1][1], 0, 0, 0); \
      acc[2][1] = __builtin_amdgcn_mfma_f32_32x32x16_bf16(aq2, BSET[1 * 4 + kw_], acc[2][1], 0, 0, 0); \
      acc[3][1] = __builtin_amdgcn_mfma_f32_32x32x16_bf16(aq3, BSET[1 * 4 + kw_], acc[3][1], 0, 0, 0); \
    }                                                                         \
  } while (0)

// 2 K-tiles per barrier: compute (C0,C1) = tiles (T,T+1); stage (T+2,T+3) -> (S0,S1).
// bA holds even tiles, bB odd (fixed roles). vmcnt(8) forces both stages, leaves LDB(T+2).
#define PHASE2(T, C0, C1, S0, S1) do {                                        \
    const int tp1_ = (T) + 1;                                                 \
    const int tp2_ = ((T) + 2) & 63;                                          \
    const int tp3_ = ((T) + 3) & 63;                                          \
    LDB(bB, tp1_);                                                            \
    STGA(S0, tp2_);                                                           \
    STGA(S1, tp3_);                                                           \
    FENCE();                                                                  \
    PRIO1(); MTILE(C0, bA); PRIO0(); FENCE();                                 \
    LDB(bA, tp2_);                                                            \
    FENCE();                                                                  \
    PRIO1(); MTILE(C1, bB); PRIO0(); FENCE();                                 \
    VM8(); BAR(); FENCE();                                                    \
  } while (0)

__global__ __launch_bounds__(512, 2) void qgemm_r14(const u16* __restrict__ Af,
                                                    const u16* __restrict__ Bf,
                                                    float* __restrict__ out) {
  __shared__ __align__(16) char AsB[4 * 32768];  // 4-deep A K-tiles, fragment-linear

  const int tid  = threadIdx.x;
  const int lane = tid & 63;
  const int wave = tid >> 6;
  const int wrow = wave >> 2;  // 0..1 -> 128 output rows
  const int wcol = wave & 3;   // 0..3 -> 64 output cols

  const int bid = blockIdx.x;
  const int sbi = bid >> 4, li = bid & 15;
  const int mb = (sbi & 7) * 4 + (li & 3);    // 0..31
  const int nb = (sbi >> 3) * 4 + (li >> 2);  // 0..15
  const int m0 = mb * 256, n0 = nb * 256;

  // A staging sources: dest unit (r*512+tid) -> mblk_local=2r+(tid>>8),
  // kw=(tid>>6)&3, lane=tid&63; frag-linear Af, +T*4096B per K-tile (r13-verified)
  const char* pA4[4];
#pragma unroll
  for (int r = 0; r < 4; ++r) {
    pA4[r] = (const char*)Af +
             (size_t)(mb * 8 + 2 * r + (tid >> 8)) * 262144 +
             (size_t)(((tid >> 6) & 3) * 64 + (tid & 63)) * 16;
  }

  // B base: fragment-linear, this wave's nblk pair (r8-verified)
  const char* pB0 = (const char*)Bf +
      ((size_t)(nb * 8) + wcol * 2) * 262144 + lane * 16;

  // A fragment read base: byte = (wrow*4+fm)*4096 + kw*1024 + lane*16 (contiguous b128)
  const int arb = wrow * 16384 + lane * 16;

  f32x16 acc[4][2];
#pragma unroll
  for (int i = 0; i < 4; ++i)
#pragma unroll
    for (int j = 0; j < 2; ++j)
      acc[i][j] = (f32x16)(0.f);

  short8 bA[8], bB[8];

  // ---- prologue: stage tiles 0,1; B(0) in flight; vmcnt(8) forces both stages ----
  STGA(0, 0);
  STGA(1, 1);
  LDB(bA, 0);
  asm volatile("s_waitcnt vmcnt(8)" ::: "memory");
  BAR(); FENCE();

  // ---- main loop: 16 iters x 4 K-tiles (2 barriers per iter) ----
  for (int it = 0; it < 16; ++it) {
    const int tb = it * 4;
    PHASE2(tb + 0, 0, 1, 2, 3);
    PHASE2(tb + 2, 2, 3, 0, 1);
  }

  asm volatile("s_waitcnt vmcnt(0)" ::: "memory");  // drain wrapped dead stages

  // ---- epilogue: 32x32 C/D: col=lane&31, row=(reg&3)+8*(reg>>2)+4*(lane>>5) ----
  const int hi = lane >> 5;
#pragma unroll
  for (int fm = 0; fm < 4; ++fm) {
#pragma unroll
    for (int fn = 0; fn < 2; ++fn) {
      const f32x16 c = acc[fm][fn];
      const int gc = n0 + wcol * 64 + fn * 32 + (lane & 31);
      const int gr0 = m0 + wrow * 128 + fm * 32 + hi * 4;
#pragma unroll
      for (int rg = 0; rg < 16; ++rg) {
        const int gr = gr0 + (rg & 3) + 8 * (rg >> 2);
        out[(size_t)gr * NDIM + gc] = c[rg];
      }
    }
  }
}

// ---------------- fallback: fused f32-input kernel (r3, proven) ----------------
#define BM 128
#define BN 128
#define BK 64
#define NKT (KDIM / BK)
#define LDA 72
__global__ __launch_bounds__(256) void qgemm_fused_f32(
    const float* __restrict__ x, const int* __restrict__ qweight,
    const int* __restrict__ qzeros, const float* __restrict__ scales,
    float* __restrict__ out) {
  __shared__ __align__(16) short As[BM * LDA];
  __shared__ __align__(16) short Bs[BN * LDA];

  const int tid = threadIdx.x;
  const int lane = tid & 63;
  const int wave = tid >> 6;
  const int wr = wave >> 1, wc = wave & 1;
  const int bid = blockIdx.x;
  const int sbq = bid >> 4, li = bid & 15;
  const int mb = (sbq & 15) * 4 + (li & 3);
  const int nb = (sbq >> 4) * 4 + (li >> 2);
  const int m0 = mb * BM, n0 = nb * BN;

  const int ncol = tid & 127;
  const int kp_base = (tid >> 7) * 4;
  const int n_g = n0 + ncol;
  const float s = scales[n_g];
  const int zw = qzeros[n_g >> 3];
  const int zp1 = ((zw >> ((n_g & 7) * 4)) & 0xF) + 1;
  const float sz = -(float)zp1 * s;

  const int arow0 = tid >> 3;
  const int acol = (tid & 7) * 8;
  const int* qwp = qweight + (size_t)kp_base * NDIM + n_g;

  f32x4 af[8];
  {
    const float* xfp = x + (size_t)(m0 + arow0) * KDIM + acol;
#pragma unroll
    for (int g = 0; g < 4; ++g) {
      af[2 * g]     = *(const f32x4*)(xfp + (size_t)g * 32 * KDIM);
      af[2 * g + 1] = *(const f32x4*)(xfp + (size_t)g * 32 * KDIM + 4);
    }
  }
  int qw0 = qwp[0], qw1 = qwp[NDIM], qw2 = qwp[2 * NDIM], qw3 = qwp[3 * NDIM];

  f32x4 acc[4][4];
#pragma unroll
  for (int i = 0; i < 4; ++i)
#pragma unroll
    for (int j = 0; j < 4; ++j)
      acc[i][j] = (f32x4)(0.f);

  const int lr = lane & 15, kh = lane >> 4;

  for (int kt = 0; kt < NKT; ++kt) {
    __syncthreads();
#pragma unroll
    for (int g = 0; g < 4; ++g) {
      short8 v;
#pragma unroll
      for (int j = 0; j < 4; ++j) {
        v[j]     = (short)f2bf(af[2 * g][j]);
        v[4 + j] = (short)f2bf(af[2 * g + 1][j]);
      }
      *(short8*)&As[(arow0 + g * 32) * LDA + acol] = v;
    }
    {
      const int qq[4] = {qw0, qw1, qw2, qw3};
#pragma unroll
      for (int r = 0; r < 4; ++r) {
        const int w = qq[r];
        short8 v;
#pragma unroll
        for (int j = 0; j < 8; ++j)
          v[j] = (short)f2bf(fmaf((float)((w >> (4 * j)) & 0xF), s, sz));
        *(short8*)&Bs[ncol * LDA + (kp_base + r) * 8] = v;
      }
    }
    if (kt + 1 < NKT) {
      const float* xp = x + (size_t)(m0 + arow0) * KDIM + (size_t)(kt + 1) * BK + acol;
#pragma unroll
      for (int g = 0; g < 4; ++g) {
        af[2 * g]     = *(const f32x4*)(xp + (size_t)g * 32 * KDIM);
        af[2 * g + 1] = *(const f32x4*)(xp + (size_t)g * 32 * KDIM + 4);
      }
      const int* p = qwp + (size_t)(kt + 1) * 8 * NDIM;
      qw0 = p[0]; qw1 = p[NDIM]; qw2 = p[2 * NDIM]; qw3 = p[3 * NDIM];
    }
    __syncthreads();
#pragma unroll
    for (int ks = 0; ks < 2; ++ks) {
      const int kb = (ks * 4 + kh) * 8;
      short8 a[4], bb[4];
#pragma unroll
      for (int mf = 0; mf < 4; ++mf)
        a[mf] = *(const short8*)&As[(wr * 64 + mf * 16 + lr) * LDA + kb];
#pragma unroll
      for (int nf = 0; nf < 4; ++nf)
        bb[nf] = *(const short8*)&Bs[(wc * 64 + nf * 16 + lr) * LDA + kb];
#pragma unroll
      for (int mf = 0; mf < 4; ++mf)
#pragma unroll
        for (int nf = 0; nf < 4; ++nf)
          acc[mf][nf] = __builtin_amdgcn_mfma_f32_16x16x32_bf16(a[mf], bb[nf], acc[mf][nf], 0, 0, 0);
    }
  }
#pragma unroll
  for (int mf = 0; mf < 4; ++mf)
#pragma unroll
    for (int nf = 0; nf < 4; ++nf) {
      const f32x4 c = acc[mf][nf];
      const int gc = n0 + wc * 64 + nf * 16 + lr;
#pragma unroll
      for (int rg = 0; rg < 4; ++rg)
        out[(size_t)(m0 + wr * 64 + mf * 16 + kh * 4 + rg) * NDIM + gc] = c[rg];
    }
}

extern "C" void kernel_launch(void* const* d_in, const int* in_sizes, int n_in,
                              void* d_out, int out_size, void* d_ws, size_t ws_size,
                              hipStream_t stream) {
  const float* x      = (const float*)d_in[0];  // fp16 ref stored as f32 on device
  const int* qweight  = (const int*)d_in[2];    // [K/8][N] int32
  const int* qzeros   = (const int*)d_in[3];    // [1][N/8] int32
  const float* scales = (const float*)d_in[4];  // fp16 ref stored as f32
  float* out = (float*)d_out;

  const size_t xb_bytes = (size_t)MDIM * KDIM * 2;  // 64 MB
  const size_t wt_bytes = (size_t)NDIM * KDIM * 2;  // 32 MB

  if (ws_size >= xb_bytes + wt_bytes) {
    u16* xf = (u16*)d_ws;
    u16* wt = (u16*)((char*)d_ws + xb_bytes);
    prep_kernel<<<18432, 256, 0, stream>>>(x, xf, qweight, qzeros, scales, wt);
    const int grid = (MDIM / 256) * (NDIM / 256);  // 512
    qgemm_r14<<<grid, 512, 0, stream>>>(xf, wt, out);
  } else {
    const int grid = (MDIM / BM) * (NDIM / BN);  // 2048
    qgemm_fused_f32<<<grid, 256, 0, stream>>>(x, qweight, qzeros, scales, out);
  }
}

// Round 16
// 182.423 us; speedup vs baseline: 2.5422x; 1.6230x over previous
//
#include <hip/hip_runtime.h>

#define MDIM 8192
#define NDIM 4096
#define KDIM 4096
#define QS 21.1666666f      // 127/6
#define INVQS (6.0f / 127.0f)

typedef __attribute__((ext_vector_type(8))) short short8;
typedef __attribute__((ext_vector_type(4))) float f32x4;
typedef __attribute__((ext_vector_type(4))) int int4v;
typedef __attribute__((ext_vector_type(16))) int i32x16;
typedef __attribute__((ext_vector_type(16))) char char16;
typedef unsigned short u16;
typedef unsigned int u32;

__device__ __forceinline__ u16 f2bf(float f) {
  return __builtin_bit_cast(u16, static_cast<__bf16>(f));
}

// ---------------- prepass: x f32 -> i8 frag-linear; W -> (q-zp1) i8 frag-linear ----
// A unit u = mblk*8192 + kblk*64 + lane (16B) holds
//   x_i8[mblk*32+(lane&31)][kblk*32 + (lane>>5)*16 + e], e=0..15
// W unit  = nblk*8192 + kblk*64 + lane holds (q-zp1)[n=nblk*32+(lane&31)][same k map]
// (zp folded EXACTLY here -> no epilogue correction needed)
__global__ __launch_bounds__(256) void prep_kernel(const float* __restrict__ x,
                                                   char* __restrict__ xi,
                                                   const int* __restrict__ qw,
                                                   const int* __restrict__ qz,
                                                   char* __restrict__ wi) {
  const int b = blockIdx.x;
  if (b < 8192) {
    const u32 u = b * 256 + threadIdx.x;      // 0..2097151
    const int lane = u & 63;
    const int kblk = (u >> 6) & 127;
    const int mblk = u >> 13;                 // 0..255
    const int m = mblk * 32 + (lane & 31);
    const int k0 = kblk * 32 + (lane >> 5) * 16;
    const float* p = x + (size_t)m * KDIM + k0;
    char16 v;
#pragma unroll
    for (int c4 = 0; c4 < 4; ++c4) {
      const f32x4 a = *(const f32x4*)(p + c4 * 4);
#pragma unroll
      for (int j = 0; j < 4; ++j) {
        const int q = __float2int_rn(fminf(fmaxf(a[j] * QS, -127.f), 127.f));
        v[c4 * 4 + j] = (char)q;
      }
    }
    *(char16*)(xi + (size_t)u * 16) = v;
  } else {
    const u32 u = (b - 8192) * 256 + threadIdx.x;  // 0..1048575
    const int lane = u & 63;
    const int kblk = (u >> 6) & 127;
    const int nblk = u >> 13;                 // 0..127
    const int n = nblk * 32 + (lane & 31);
    const int kp0 = kblk * 4 + (lane >> 5) * 2;    // 16 k = 2 packed int32
    const int zw = qz[n >> 3];
    const int zp1 = ((zw >> ((n & 7) * 4)) & 0xF) + 1;
    char16 v;
#pragma unroll
    for (int h = 0; h < 2; ++h) {
      const int w = qw[(size_t)(kp0 + h) * NDIM + n];
#pragma unroll
      for (int j = 0; j < 8; ++j)
        v[h * 8 + j] = (char)(((w >> (4 * j)) & 0xF) - zp1);
    }
    *(char16*)(wi + (size_t)u * 16) = v;
  }
}

// ---------------- main GEMM: i8 32x32x32, r14 schedule, K-tile = 128 k ----------------
#define BAR()    __builtin_amdgcn_s_barrier()
#define FENCE()  __builtin_amdgcn_sched_barrier(0)
#define VM8()    asm volatile("s_waitcnt vmcnt(8)" ::: "memory")
#define PRIO1()  __builtin_amdgcn_s_setprio(1)
#define PRIO0()  __builtin_amdgcn_s_setprio(0)

// stage A K-tile T (256 rows x 128 k i8 = 32KB) into buffer BUF: 4 glds rounds
#define STGA(BUF, T) do {                                                     \
    _Pragma("unroll")                                                         \
    for (int r_ = 0; r_ < 4; ++r_) {                                          \
      __builtin_amdgcn_global_load_lds(                                       \
        (const __attribute__((address_space(1))) void*)                       \
          (pA4[r_] + (size_t)(T) * 4096),                                     \
        (__attribute__((address_space(3))) void*)                             \
          (AsB + (BUF) * 32768 + r_ * 8192 + tid * 16), 16, 0, 0);            \
    }                                                                         \
  } while (0)

// load K-tile TN's 8 B-fragments (fn 0..1 x kw 0..3, 1KB each) into DST
#define LDB(DST, TN) do {                                                     \
    _Pragma("unroll")                                                         \
    for (int fn_ = 0; fn_ < 2; ++fn_)                                         \
      _Pragma("unroll")                                                       \
      for (int kw_ = 0; kw_ < 4; ++kw_)                                       \
        DST[fn_ * 4 + kw_] = *(const int4v*)(pB0 + (size_t)fn_ * 131072 +     \
            (size_t)(TN) * 4096 + kw_ * 1024);                                \
  } while (0)

// MFMA one K-tile (128 k) from A-LDS buffer BUF with B register set BSET
#define MTILE(BUF, BSET) do {                                                 \
    _Pragma("unroll")                                                         \
    for (int kw_ = 0; kw_ < 4; ++kw_) {                                       \
      const char* b_ = AsB + (BUF) * 32768 + arb + kw_ * 1024;                \
      int4v aq0 = *(const int4v*)(b_);                                        \
      int4v aq1 = *(const int4v*)(b_ + 4096);                                 \
      int4v aq2 = *(const int4v*)(b_ + 8192);                                 \
      int4v aq3 = *(const int4v*)(b_ + 12288);                                \
      acc[0][0] = __builtin_amdgcn_mfma_i32_32x32x32_i8(aq0, BSET[0 * 4 + kw_], acc[0][0], 0, 0, 0); \
      acc[1][0] = __builtin_amdgcn_mfma_i32_32x32x32_i8(aq1, BSET[0 * 4 + kw_], acc[1][0], 0, 0, 0); \
      acc[2][0] = __builtin_amdgcn_mfma_i32_32x32x32_i8(aq2, BSET[0 * 4 + kw_], acc[2][0], 0, 0, 0); \
      acc[3][0] = __builtin_amdgcn_mfma_i32_32x32x32_i8(aq3, BSET[0 * 4 + kw_], acc[3][0], 0, 0, 0); \
      acc[0][1] = __builtin_amdgcn_mfma_i32_32x32x32_i8(aq0, BSET[1 * 4 + kw_], acc[0][1], 0, 0, 0); \
      acc[1][1] = __builtin_amdgcn_mfma_i32_32x32x32_i8(aq1, BSET[1 * 4 + kw_], acc[1][1], 0, 0, 0); \
      acc[2][1] = __builtin_amdgcn_mfma_i32_32x32x32_i8(aq2, BSET[1 * 4 + kw_], acc[2][1], 0, 0, 0); \
      acc[3][1] = __builtin_amdgcn_mfma_i32_32x32x32_i8(aq3, BSET[1 * 4 + kw_], acc[3][1], 0, 0, 0); \
    }                                                                         \
  } while (0)

// 2 K-tiles per barrier (r14-verified ledger): vmcnt(8) forces both stages
#define PHASE2(T, C0, C1, S0, S1) do {                                        \
    const int tp1_ = (T) + 1;                                                 \
    const int tp2_ = ((T) + 2) & 31;                                          \
    const int tp3_ = ((T) + 3) & 31;                                          \
    LDB(bB, tp1_);                                                            \
    STGA(S0, tp2_);                                                           \
    STGA(S1, tp3_);                                                           \
    FENCE();                                                                  \
    PRIO1(); MTILE(C0, bA); PRIO0(); FENCE();                                 \
    LDB(bA, tp2_);                                                            \
    FENCE();                                                                  \
    PRIO1(); MTILE(C1, bB); PRIO0(); FENCE();                                 \
    VM8(); BAR(); FENCE();                                                    \
  } while (0)

__global__ __launch_bounds__(512, 2) void qgemm_i8(const char* __restrict__ Ai,
                                                   const char* __restrict__ Bi,
                                                   const float* __restrict__ scales,
                                                   float* __restrict__ out) {
  __shared__ __align__(16) char AsB[4 * 32768];  // 4-deep A K-tiles (128 k each)

  const int tid  = threadIdx.x;
  const int lane = tid & 63;
  const int wave = tid >> 6;
  const int wrow = wave >> 2;  // 0..1 -> 128 output rows
  const int wcol = wave & 3;   // 0..3 -> 64 output cols

  const int bid = blockIdx.x;
  const int sbi = bid >> 4, li = bid & 15;
  const int mb = (sbi & 7) * 4 + (li & 3);    // 0..31
  const int nb = (sbi >> 3) * 4 + (li >> 2);  // 0..15
  const int m0 = mb * 256, n0 = nb * 256;

  // A staging sources: dest unit (r*512+tid) -> mblk_local = 2r+(tid>>8),
  // kw=(tid>>6)&3, lane=tid&63; mblk section = 131072 B, K-tile = 4096 B
  const char* pA4[4];
#pragma unroll
  for (int r = 0; r < 4; ++r) {
    pA4[r] = Ai + (size_t)(mb * 8 + 2 * r + (tid >> 8)) * 131072 +
             (size_t)(((tid >> 6) & 3) * 64 + (tid & 63)) * 16;
  }

  // B base: fragment-linear, this wave's nblk pair
  const char* pB0 = Bi + (size_t)(nb * 8 + wcol * 2) * 131072 + lane * 16;

  // A fragment read base: byte = (wrow*4+fm)*4096 + kw*1024 + lane*16
  const int arb = wrow * 16384 + lane * 16;

  i32x16 acc[4][2];
#pragma unroll
  for (int i = 0; i < 4; ++i)
#pragma unroll
    for (int j = 0; j < 2; ++j)
      acc[i][j] = (i32x16)(0);

  int4v bA[8], bB[8];

  // ---- prologue: stage tiles 0,1; B(0) in flight; vmcnt(8) forces stages ----
  STGA(0, 0);
  STGA(1, 1);
  LDB(bA, 0);
  asm volatile("s_waitcnt vmcnt(8)" ::: "memory");
  BAR(); FENCE();

  // ---- main loop: 8 iters x 4 K-tiles (2 barriers per iter); 32 tiles total ----
  for (int it = 0; it < 8; ++it) {
    const int tb = it * 4;
    PHASE2(tb + 0, 0, 1, 2, 3);
    PHASE2(tb + 2, 2, 3, 0, 1);
  }

  asm volatile("s_waitcnt vmcnt(0)" ::: "memory");  // drain wrapped dead stages

  // ---- epilogue: C/D col=lane&31, row=(reg&3)+8*(reg>>2)+4*(lane>>5);
  //      out = (s[n]/QS) * acc   (zp already folded exactly into Bi) ----
  const int hi = lane >> 5;
#pragma unroll
  for (int fm = 0; fm < 4; ++fm) {
    const int gr0 = m0 + wrow * 128 + fm * 32 + hi * 4;
#pragma unroll
    for (int fn = 0; fn < 2; ++fn) {
      const i32x16 c = acc[fm][fn];
      const int gc = n0 + wcol * 64 + fn * 32 + (lane & 31);
      const float sn = scales[gc] * INVQS;
#pragma unroll
      for (int rg = 0; rg < 16; ++rg) {
        const int gr = gr0 + (rg & 3) + 8 * (rg >> 2);
        out[(size_t)gr * NDIM + gc] = sn * (float)c[rg];
      }
    }
  }
}

// ---------------- fallback: fused f32-input kernel (r3, proven) ----------------
#define BM 128
#define BN 128
#define BK 64
#define NKT (KDIM / BK)
#define LDA 72
__global__ __launch_bounds__(256) void qgemm_fused_f32(
    const float* __restrict__ x, const int* __restrict__ qweight,
    const int* __restrict__ qzeros, const float* __restrict__ scales,
    float* __restrict__ out) {
  __shared__ __align__(16) short As[BM * LDA];
  __shared__ __align__(16) short Bs[BN * LDA];

  const int tid = threadIdx.x;
  const int lane = tid & 63;
  const int wave = tid >> 6;
  const int wr = wave >> 1, wc = wave & 1;
  const int bid = blockIdx.x;
  const int sbq = bid >> 4, li = bid & 15;
  const int mb = (sbq & 15) * 4 + (li & 3);
  const int nb = (sbq >> 4) * 4 + (li >> 2);
  const int m0 = mb * BM, n0 = nb * BN;

  const int ncol = tid & 127;
  const int kp_base = (tid >> 7) * 4;
  const int n_g = n0 + ncol;
  const float s = scales[n_g];
  const int zw = qzeros[n_g >> 3];
  const int zp1 = ((zw >> ((n_g & 7) * 4)) & 0xF) + 1;
  const float sz = -(float)zp1 * s;

  const int arow0 = tid >> 3;
  const int acol = (tid & 7) * 8;
  const int* qwp = qweight + (size_t)kp_base * NDIM + n_g;

  f32x4 af[8];
  {
    const float* xfp = x + (size_t)(m0 + arow0) * KDIM + acol;
#pragma unroll
    for (int g = 0; g < 4; ++g) {
      af[2 * g]     = *(const f32x4*)(xfp + (size_t)g * 32 * KDIM);
      af[2 * g + 1] = *(const f32x4*)(xfp + (size_t)g * 32 * KDIM + 4);
    }
  }
  int qw0 = qwp[0], qw1 = qwp[NDIM], qw2 = qwp[2 * NDIM], qw3 = qwp[3 * NDIM];

  f32x4 acc[4][4];
#pragma unroll
  for (int i = 0; i < 4; ++i)
#pragma unroll
    for (int j = 0; j < 4; ++j)
      acc[i][j] = (f32x4)(0.f);

  const int lr = lane & 15, kh = lane >> 4;

  for (int kt = 0; kt < NKT; ++kt) {
    __syncthreads();
#pragma unroll
    for (int g = 0; g < 4; ++g) {
      short8 v;
#pragma unroll
      for (int j = 0; j < 4; ++j) {
        v[j]     = (short)f2bf(af[2 * g][j]);
        v[4 + j] = (short)f2bf(af[2 * g + 1][j]);
      }
      *(short8*)&As[(arow0 + g * 32) * LDA + acol] = v;
    }
    {
      const int qq[4] = {qw0, qw1, qw2, qw3};
#pragma unroll
      for (int r = 0; r < 4; ++r) {
        const int w = qq[r];
        short8 v;
#pragma unroll
        for (int j = 0; j < 8; ++j)
          v[j] = (short)f2bf(fmaf((float)((w >> (4 * j)) & 0xF), s, sz));
        *(short8*)&Bs[ncol * LDA + (kp_base + r) * 8] = v;
      }
    }
    if (kt + 1 < NKT) {
      const float* xp = x + (size_t)(m0 + arow0) * KDIM + (size_t)(kt + 1) * BK + acol;
#pragma unroll
      for (int g = 0; g < 4; ++g) {
        af[2 * g]     = *(const f32x4*)(xp + (size_t)g * 32 * KDIM);
        af[2 * g + 1] = *(const f32x4*)(xp + (size_t)g * 32 * KDIM + 4);
      }
      const int* p = qwp + (size_t)(kt + 1) * 8 * NDIM;
      qw0 = p[0]; qw1 = p[NDIM]; qw2 = p[2 * NDIM]; qw3 = p[3 * NDIM];
    }
    __syncthreads();
#pragma unroll
    for (int ks = 0; ks < 2; ++ks) {
      const int kb = (ks * 4 + kh) * 8;
      short8 a[4], bb[4];
#pragma unroll
      for (int mf = 0; mf < 4; ++mf)
        a[mf] = *(const short8*)&As[(wr * 64 + mf * 16 + lr) * LDA + kb];
#pragma unroll
      for (int nf = 0; nf < 4; ++nf)
        bb[nf] = *(const short8*)&Bs[(wc * 64 + nf * 16 + lr) * LDA + kb];
#pragma unroll
      for (int mf = 0; mf < 4; ++mf)
#pragma unroll
        for (int nf = 0; nf < 4; ++nf)
          acc[mf][nf] = __builtin_amdgcn_mfma_f32_16x16x32_bf16(a[mf], bb[nf], acc[mf][nf], 0, 0, 0);
    }
  }
#pragma unroll
  for (int mf = 0; mf < 4; ++mf)
#pragma unroll
    for (int nf = 0; nf < 4; ++nf) {
      const f32x4 c = acc[mf][nf];
      const int gc = n0 + wc * 64 + nf * 16 + lr;
#pragma unroll
      for (int rg = 0; rg < 4; ++rg)
        out[(size_t)(m0 + wr * 64 + mf * 16 + kh * 4 + rg) * NDIM + gc] = c[rg];
    }
}

extern "C" void kernel_launch(void* const* d_in, const int* in_sizes, int n_in,
                              void* d_out, int out_size, void* d_ws, size_t ws_size,
                              hipStream_t stream) {
  const float* x      = (const float*)d_in[0];  // fp16 ref stored as f32 on device
  const int* qweight  = (const int*)d_in[2];    // [K/8][N] int32
  const int* qzeros   = (const int*)d_in[3];    // [1][N/8] int32
  const float* scales = (const float*)d_in[4];  // fp16 ref stored as f32
  float* out = (float*)d_out;

  const size_t xi_bytes = (size_t)MDIM * KDIM;      // 32 MB
  const size_t wi_bytes = (size_t)NDIM * KDIM;      // 16 MB

  if (ws_size >= xi_bytes + wi_bytes) {
    char* xi = (char*)d_ws;
    char* wi = (char*)d_ws + xi_bytes;
    prep_kernel<<<8192 + 4096, 256, 0, stream>>>(x, xi, qweight, qzeros, wi);
    const int grid = (MDIM / 256) * (NDIM / 256);  // 512
    qgemm_i8<<<grid, 512, 0, stream>>>(xi, wi, scales, out);
  } else {
    const int grid = (MDIM / BM) * (NDIM / BN);  // 2048
    qgemm_fused_f32<<<grid, 256, 0, stream>>>(x, qweight, qzeros, scales, out);
  }
}

// Round 17
// 174.507 us; speedup vs baseline: 2.6575x; 1.0454x over previous
//
#include <hip/hip_runtime.h>

#define MDIM 8192
#define NDIM 4096
#define KDIM 4096
#define QS 21.1666666f      // 127/6
#define INVQS (6.0f / 127.0f)

typedef __attribute__((ext_vector_type(8))) short short8;
typedef __attribute__((ext_vector_type(4))) float f32x4;
typedef __attribute__((ext_vector_type(4))) int int4v;
typedef __attribute__((ext_vector_type(16))) int i32x16;
typedef __attribute__((ext_vector_type(16))) char char16;
typedef unsigned short u16;
typedef unsigned int u32;

__device__ __forceinline__ u16 f2bf(float f) {
  return __builtin_bit_cast(u16, static_cast<__bf16>(f));
}

// ---------------- prepass: x f32 -> i8 frag-linear; W -> (q-zp1) i8 frag-linear ----
// (r16-verified; numerics frozen)
__global__ __launch_bounds__(256) void prep_kernel(const float* __restrict__ x,
                                                   char* __restrict__ xi,
                                                   const int* __restrict__ qw,
                                                   const int* __restrict__ qz,
                                                   char* __restrict__ wi) {
  const int b = blockIdx.x;
  if (b < 8192) {
    const u32 u = b * 256 + threadIdx.x;      // 0..2097151
    const int lane = u & 63;
    const int kblk = (u >> 6) & 127;
    const int mblk = u >> 13;                 // 0..255
    const int m = mblk * 32 + (lane & 31);
    const int k0 = kblk * 32 + (lane >> 5) * 16;
    const float* p = x + (size_t)m * KDIM + k0;
    char16 v;
#pragma unroll
    for (int c4 = 0; c4 < 4; ++c4) {
      const f32x4 a = *(const f32x4*)(p + c4 * 4);
#pragma unroll
      for (int j = 0; j < 4; ++j) {
        const int q = __float2int_rn(fminf(fmaxf(a[j] * QS, -127.f), 127.f));
        v[c4 * 4 + j] = (char)q;
      }
    }
    *(char16*)(xi + (size_t)u * 16) = v;
  } else {
    const u32 u = (b - 8192) * 256 + threadIdx.x;  // 0..1048575
    const int lane = u & 63;
    const int kblk = (u >> 6) & 127;
    const int nblk = u >> 13;                 // 0..127
    const int n = nblk * 32 + (lane & 31);
    const int kp0 = kblk * 4 + (lane >> 5) * 2;
    const int zw = qz[n >> 3];
    const int zp1 = ((zw >> ((n & 7) * 4)) & 0xF) + 1;
    char16 v;
#pragma unroll
    for (int h = 0; h < 2; ++h) {
      const int w = qw[(size_t)(kp0 + h) * NDIM + n];
#pragma unroll
      for (int j = 0; j < 8; ++j)
        v[h * 8 + j] = (char)(((w >> (4 * j)) & 0xF) - zp1);
    }
    *(char16*)(wi + (size_t)u * 16) = v;
  }
}

// ---------------- main GEMM: i8 32x32x32, 128x256 tile, 4 waves, 2 blocks/CU ----------
#define BAR()    __builtin_amdgcn_s_barrier()
#define FENCE()  __builtin_amdgcn_sched_barrier(0)
#define VM8()    asm volatile("s_waitcnt vmcnt(8)" ::: "memory")
#define PRIO1()  __builtin_amdgcn_s_setprio(1)
#define PRIO0()  __builtin_amdgcn_s_setprio(0)

// stage A K-tile T (128 rows x 128 k i8 = 16KB) into buffer BUF: 4 glds rounds
#define STGA(BUF, T) do {                                                     \
    _Pragma("unroll")                                                         \
    for (int r_ = 0; r_ < 4; ++r_) {                                          \
      __builtin_amdgcn_global_load_lds(                                       \
        (const __attribute__((address_space(1))) void*)                       \
          (pA4[r_] + (size_t)(T) * 4096),                                     \
        (__attribute__((address_space(3))) void*)                             \
          (AsB + (BUF) * 16384 + r_ * 4096 + tid * 16), 16, 0, 0);            \
    }                                                                         \
  } while (0)

// load K-tile TN's 8 B-fragments (fn 0..1 x kw 0..3, 1KB each) into DST
#define LDB(DST, TN) do {                                                     \
    _Pragma("unroll")                                                         \
    for (int fn_ = 0; fn_ < 2; ++fn_)                                         \
      _Pragma("unroll")                                                       \
      for (int kw_ = 0; kw_ < 4; ++kw_)                                       \
        DST[fn_ * 4 + kw_] = *(const int4v*)(pB0 + (size_t)fn_ * 131072 +     \
            (size_t)(TN) * 4096 + kw_ * 1024);                                \
  } while (0)

// MFMA one K-tile (128 k) from A-LDS buffer BUF with B register set BSET
#define MTILE(BUF, BSET) do {                                                 \
    _Pragma("unroll")                                                         \
    for (int kw_ = 0; kw_ < 4; ++kw_) {                                       \
      const char* b_ = AsB + (BUF) * 16384 + arb + kw_ * 1024;                \
      int4v aq0 = *(const int4v*)(b_);                                        \
      int4v aq1 = *(const int4v*)(b_ + 4096);                                 \
      int4v aq2 = *(const int4v*)(b_ + 8192);                                 \
      int4v aq3 = *(const int4v*)(b_ + 12288);                                \
      acc[0][0] = __builtin_amdgcn_mfma_i32_32x32x32_i8(aq0, BSET[0 * 4 + kw_], acc[0][0], 0, 0, 0); \
      acc[1][0] = __builtin_amdgcn_mfma_i32_32x32x32_i8(aq1, BSET[0 * 4 + kw_], acc[1][0], 0, 0, 0); \
      acc[2][0] = __builtin_amdgcn_mfma_i32_32x32x32_i8(aq2, BSET[0 * 4 + kw_], acc[2][0], 0, 0, 0); \
      acc[3][0] = __builtin_amdgcn_mfma_i32_32x32x32_i8(aq3, BSET[0 * 4 + kw_], acc[3][0], 0, 0, 0); \
      acc[0][1] = __builtin_amdgcn_mfma_i32_32x32x32_i8(aq0, BSET[1 * 4 + kw_], acc[0][1], 0, 0, 0); \
      acc[1][1] = __builtin_amdgcn_mfma_i32_32x32x32_i8(aq1, BSET[1 * 4 + kw_], acc[1][1], 0, 0, 0); \
      acc[2][1] = __builtin_amdgcn_mfma_i32_32x32x32_i8(aq2, BSET[1 * 4 + kw_], acc[2][1], 0, 0, 0); \
      acc[3][1] = __builtin_amdgcn_mfma_i32_32x32x32_i8(aq3, BSET[1 * 4 + kw_], acc[3][1], 0, 0, 0); \
    }                                                                         \
  } while (0)

// 2 K-tiles per barrier (r14/r16-verified ledger): vmcnt(8) forces both stages
#define PHASE2(T, C0, C1, S0, S1) do {                                        \
    const int tp1_ = (T) + 1;                                                 \
    const int tp2_ = ((T) + 2) & 31;                                          \
    const int tp3_ = ((T) + 3) & 31;                                          \
    LDB(bB, tp1_);                                                            \
    STGA(S0, tp2_);                                                           \
    STGA(S1, tp3_);                                                           \
    FENCE();                                                                  \
    PRIO1(); MTILE(C0, bA); PRIO0(); FENCE();                                 \
    LDB(bA, tp2_);                                                            \
    FENCE();                                                                  \
    PRIO1(); MTILE(C1, bB); PRIO0(); FENCE();                                 \
    VM8(); BAR(); FENCE();                                                    \
  } while (0)

__global__ __launch_bounds__(256, 2) void qgemm_i8_db(const char* __restrict__ Ai,
                                                      const char* __restrict__ Bi,
                                                      const float* __restrict__ scales,
                                                      float* __restrict__ out) {
  __shared__ __align__(16) char AsB[4 * 16384];  // 4-deep A K-tiles (128 rows x 128 k)

  const int tid  = threadIdx.x;
  const int lane = tid & 63;
  const int wcol = tid >> 6;   // 0..3 -> 64 output cols each (4 waves, 1 wave-row)

  const int bid = blockIdx.x;                  // 0..1023
  const int sbi = bid >> 4, li = bid & 15;
  const int mb = (sbi & 15) * 4 + (li & 3);    // 0..63
  const int nb = (sbi >> 4) * 4 + (li >> 2);   // 0..15
  const int m0 = mb * 128, n0 = nb * 256;

  // A staging sources: dest unit (r*256+tid) -> mblk_local = r, kw=(tid>>6)&3,
  // lane=tid&63; mblk section = 131072 B, K-tile = 4096 B (r16-verified map)
  const char* pA4[4];
#pragma unroll
  for (int r = 0; r < 4; ++r) {
    pA4[r] = Ai + (size_t)(mb * 4 + r) * 131072 +
             (size_t)(((tid >> 6) & 3) * 64 + (tid & 63)) * 16;
  }

  // B base: fragment-linear, this wave's nblk pair
  const char* pB0 = Bi + (size_t)(nb * 8 + wcol * 2) * 131072 + lane * 16;

  // A fragment read base: byte = fm*4096 + kw*1024 + lane*16 (contiguous b128)
  const int arb = lane * 16;

  i32x16 acc[4][2];
#pragma unroll
  for (int i = 0; i < 4; ++i)
#pragma unroll
    for (int j = 0; j < 2; ++j)
      acc[i][j] = (i32x16)(0);

  int4v bA[8], bB[8];

  // ---- prologue: stage tiles 0,1; B(0) in flight; vmcnt(8) forces stages ----
  STGA(0, 0);
  STGA(1, 1);
  LDB(bA, 0);
  asm volatile("s_waitcnt vmcnt(8)" ::: "memory");
  BAR(); FENCE();

  // ---- main loop: 8 iters x 4 K-tiles (2 barriers per iter); 32 tiles total ----
  for (int it = 0; it < 8; ++it) {
    const int tb = it * 4;
    PHASE2(tb + 0, 0, 1, 2, 3);
    PHASE2(tb + 2, 2, 3, 0, 1);
  }

  asm volatile("s_waitcnt vmcnt(0)" ::: "memory");  // drain wrapped dead stages

  // ---- epilogue: C/D col=lane&31, row=(reg&3)+8*(reg>>2)+4*(lane>>5);
  //      out = (s[n]/QS) * acc   (zp folded exactly into Bi) ----
  const int hi = lane >> 5;
#pragma unroll
  for (int fm = 0; fm < 4; ++fm) {
    const int gr0 = m0 + fm * 32 + hi * 4;
#pragma unroll
    for (int fn = 0; fn < 2; ++fn) {
      const i32x16 c = acc[fm][fn];
      const int gc = n0 + wcol * 64 + fn * 32 + (lane & 31);
      const float sn = scales[gc] * INVQS;
#pragma unroll
      for (int rg = 0; rg < 16; ++rg) {
        const int gr = gr0 + (rg & 3) + 8 * (rg >> 2);
        out[(size_t)gr * NDIM + gc] = sn * (float)c[rg];
      }
    }
  }
}

// ---------------- fallback: fused f32-input kernel (r3, proven) ----------------
#define BM 128
#define BN 128
#define BK 64
#define NKT (KDIM / BK)
#define LDA 72
__global__ __launch_bounds__(256) void qgemm_fused_f32(
    const float* __restrict__ x, const int* __restrict__ qweight,
    const int* __restrict__ qzeros, const float* __restrict__ scales,
    float* __restrict__ out) {
  __shared__ __align__(16) short As[BM * LDA];
  __shared__ __align__(16) short Bs[BN * LDA];

  const int tid = threadIdx.x;
  const int lane = tid & 63;
  const int wave = tid >> 6;
  const int wr = wave >> 1, wc = wave & 1;
  const int bid = blockIdx.x;
  const int sbq = bid >> 4, li = bid & 15;
  const int mb = (sbq & 15) * 4 + (li & 3);
  const int nb = (sbq >> 4) * 4 + (li >> 2);
  const int m0 = mb * BM, n0 = nb * BN;

  const int ncol = tid & 127;
  const int kp_base = (tid >> 7) * 4;
  const int n_g = n0 + ncol;
  const float s = scales[n_g];
  const int zw = qzeros[n_g >> 3];
  const int zp1 = ((zw >> ((n_g & 7) * 4)) & 0xF) + 1;
  const float sz = -(float)zp1 * s;

  const int arow0 = tid >> 3;
  const int acol = (tid & 7) * 8;
  const int* qwp = qweight + (size_t)kp_base * NDIM + n_g;

  f32x4 af[8];
  {
    const float* xfp = x + (size_t)(m0 + arow0) * KDIM + acol;
#pragma unroll
    for (int g = 0; g < 4; ++g) {
      af[2 * g]     = *(const f32x4*)(xfp + (size_t)g * 32 * KDIM);
      af[2 * g + 1] = *(const f32x4*)(xfp + (size_t)g * 32 * KDIM + 4);
    }
  }
  int qw0 = qwp[0], qw1 = qwp[NDIM], qw2 = qwp[2 * NDIM], qw3 = qwp[3 * NDIM];

  f32x4 acc[4][4];
#pragma unroll
  for (int i = 0; i < 4; ++i)
#pragma unroll
    for (int j = 0; j < 4; ++j)
      acc[i][j] = (f32x4)(0.f);

  const int lr = lane & 15, kh = lane >> 4;

  for (int kt = 0; kt < NKT; ++kt) {
    __syncthreads();
#pragma unroll
    for (int g = 0; g < 4; ++g) {
      short8 v;
#pragma unroll
      for (int j = 0; j < 4; ++j) {
        v[j]     = (short)f2bf(af[2 * g][j]);
        v[4 + j] = (short)f2bf(af[2 * g + 1][j]);
      }
      *(short8*)&As[(arow0 + g * 32) * LDA + acol] = v;
    }
    {
      const int qq[4] = {qw0, qw1, qw2, qw3};
#pragma unroll
      for (int r = 0; r < 4; ++r) {
        const int w = qq[r];
        short8 v;
#pragma unroll
        for (int j = 0; j < 8; ++j)
          v[j] = (short)f2bf(fmaf((float)((w >> (4 * j)) & 0xF), s, sz));
        *(short8*)&Bs[ncol * LDA + (kp_base + r) * 8] = v;
      }
    }
    if (kt + 1 < NKT) {
      const float* xp = x + (size_t)(m0 + arow0) * KDIM + (size_t)(kt + 1) * BK + acol;
#pragma unroll
      for (int g = 0; g < 4; ++g) {
        af[2 * g]     = *(const f32x4*)(xp + (size_t)g * 32 * KDIM);
        af[2 * g + 1] = *(const f32x4*)(xp + (size_t)g * 32 * KDIM + 4);
      }
      const int* p = qwp + (size_t)(kt + 1) * 8 * NDIM;
      qw0 = p[0]; qw1 = p[NDIM]; qw2 = p[2 * NDIM]; qw3 = p[3 * NDIM];
    }
    __syncthreads();
#pragma unroll
    for (int ks = 0; ks < 2; ++ks) {
      const int kb = (ks * 4 + kh) * 8;
      short8 a[4], bb[4];
#pragma unroll
      for (int mf = 0; mf < 4; ++mf)
        a[mf] = *(const short8*)&As[(wr * 64 + mf * 16 + lr) * LDA + kb];
#pragma unroll
      for (int nf = 0; nf < 4; ++nf)
        bb[nf] = *(const short8*)&Bs[(wc * 64 + nf * 16 + lr) * LDA + kb];
#pragma unroll
      for (int mf = 0; mf < 4; ++mf)
#pragma unroll
        for (int nf = 0; nf < 4; ++nf)
          acc[mf][nf] = __builtin_amdgcn_mfma_f32_16x16x32_bf16(a[mf], bb[nf], acc[mf][nf], 0, 0, 0);
    }
  }
#pragma unroll
  for (int mf = 0; mf < 4; ++mf)
#pragma unroll
    for (int nf = 0; nf < 4; ++nf) {
      const f32x4 c = acc[mf][nf];
      const int gc = n0 + wc * 64 + nf * 16 + lr;
#pragma unroll
      for (int rg = 0; rg < 4; ++rg)
        out[(size_t)(m0 + wr * 64 + mf * 16 + kh * 4 + rg) * NDIM + gc] = c[rg];
    }
}

extern "C" void kernel_launch(void* const* d_in, const int* in_sizes, int n_in,
                              void* d_out, int out_size, void* d_ws, size_t ws_size,
                              hipStream_t stream) {
  const float* x      = (const float*)d_in[0];  // fp16 ref stored as f32 on device
  const int* qweight  = (const int*)d_in[2];    // [K/8][N] int32
  const int* qzeros   = (const int*)d_in[3];    // [1][N/8] int32
  const float* scales = (const float*)d_in[4];  // fp16 ref stored as f32
  float* out = (float*)d_out;

  const size_t xi_bytes = (size_t)MDIM * KDIM;      // 32 MB
  const size_t wi_bytes = (size_t)NDIM * KDIM;      // 16 MB

  if (ws_size >= xi_bytes + wi_bytes) {
    char* xi = (char*)d_ws;
    char* wi = (char*)d_ws + xi_bytes;
    prep_kernel<<<8192 + 4096, 256, 0, stream>>>(x, xi, qweight, qzeros, wi);
    const int grid = (MDIM / 128) * (NDIM / 256);  // 1024
    qgemm_i8_db<<<grid, 256, 0, stream>>>(xi, wi, scales, out);
  } else {
    const int grid = (MDIM / BM) * (NDIM / BN);  // 2048
    qgemm_fused_f32<<<grid, 256, 0, stream>>>(x, qweight, qzeros, scales, out);
  }
}